// Round 1
// baseline (5461.122 us; speedup 1.0000x reference)
//
#include <hip/hip_runtime.h>

typedef unsigned short u16;
typedef unsigned long long u64;
typedef __attribute__((ext_vector_type(8))) short bf16x8;
typedef __attribute__((ext_vector_type(4))) float f32x4;

#define DEVI __device__ __forceinline__

DEVI u16 f2b(float f) {
  unsigned u = __float_as_uint(f);
  u += 0x7fffu + ((u >> 16) & 1u);
  return (u16)(u >> 16);
}
DEVI float gelu_f(float x) { return 0.5f * x * (1.f + erff(x * 0.70710678118654752f)); }
DEVI float sigm_f(float x) { return 1.f / (1.f + expf(-x)); }

DEVI void gload16(const void* g, void* l) {
  __builtin_amdgcn_global_load_lds((__attribute__((address_space(1))) void*)g,
                                   (__attribute__((address_space(3))) void*)l, 16, 0, 0);
}

// ---------------------------------------------------------------------------
// Generic batched GEMM:  C[z] = act(A[z] (MxK) @ Bt[z]^T + bias), Bt is (N x K).
// flags: 1=gelu, 2=bias, 4=store f32, 8=store bf16
// batch offsets: A += z*sA ; Bt += (z/nH)*sBb + (z%nH)*sBh ; C += z*sC
// Requires K % 64 == 0. M,N bounds handled (clamped stage + guarded store).
// ---------------------------------------------------------------------------
__global__ __launch_bounds__(256) void gemm_bt(
    const u16* __restrict__ A, const u16* __restrict__ Bt,
    const float* __restrict__ bias, float* __restrict__ C32, u16* __restrict__ C16,
    int M, int N, int K, int ldA, int ldB, int ldC,
    long long sA, long long sBb, long long sBh, long long sC, int nH, int flags)
{
  __shared__ __align__(16) u16 As[128 * 64];
  __shared__ __align__(16) u16 Bs[128 * 64];
  const int z = blockIdx.z;
  const int zb = z / nH, zh = z - zb * nH;
  A  += (long long)z * sA;
  Bt += (long long)zb * sBb + (long long)zh * sBh;
  const long long cOff = (long long)z * sC;
  const int m0 = blockIdx.x * 128, n0 = blockIdx.y * 128;
  const int t = threadIdx.x, lane = t & 63;
  const int wm = ((t >> 7) & 1) * 64, wn = ((t >> 6) & 1) * 64;

  f32x4 acc[4][4];
#pragma unroll
  for (int i = 0; i < 4; ++i)
#pragma unroll
    for (int j = 0; j < 4; ++j) { f32x4 zz = {0.f, 0.f, 0.f, 0.f}; acc[i][j] = zz; }

  for (int k0 = 0; k0 < K; k0 += 64) {
#pragma unroll
    for (int r = 0; r < 4; ++r) {
      const int c = r * 256 + t;
      const int row = c >> 3;
      const int col = (c & 7) << 3;
      int ga = m0 + row; if (ga >= M) ga = M - 1;
      gload16(A + (long long)ga * ldA + (k0 + col), &As[(size_t)(r * 256 + (t & 192)) * 8]);
      int gb = n0 + row; if (gb >= N) gb = N - 1;
      gload16(Bt + (long long)gb * ldB + (k0 + col), &Bs[(size_t)(r * 256 + (t & 192)) * 8]);
    }
    __syncthreads();
#pragma unroll
    for (int ks = 0; ks < 2; ++ks) {
      const int ko = ks * 32 + ((lane >> 4) << 3);
      bf16x8 af[4], bfv[4];
#pragma unroll
      for (int i = 0; i < 4; ++i)
        af[i] = *(const bf16x8*)&As[(wm + i * 16 + (lane & 15)) * 64 + ko];
#pragma unroll
      for (int i = 0; i < 4; ++i)
        bfv[i] = *(const bf16x8*)&Bs[(wn + i * 16 + (lane & 15)) * 64 + ko];
#pragma unroll
      for (int mi = 0; mi < 4; ++mi)
#pragma unroll
        for (int ni = 0; ni < 4; ++ni)
          acc[mi][ni] = __builtin_amdgcn_mfma_f32_16x16x32_bf16(af[mi], bfv[ni], acc[mi][ni], 0, 0, 0);
    }
    __syncthreads();
  }

  const int cb = n0 + wn + (lane & 15);
  const int rb = m0 + wm + ((lane >> 4) << 2);
#pragma unroll
  for (int ni = 0; ni < 4; ++ni) {
    const int col = cb + ni * 16;
    if (col >= N) continue;
    const float bv = (flags & 2) ? bias[col] : 0.f;
#pragma unroll
    for (int mi = 0; mi < 4; ++mi) {
#pragma unroll
      for (int q = 0; q < 4; ++q) {
        const int row = rb + mi * 16 + q;
        if (row >= M) continue;
        float x = acc[mi][ni][q] + bv;
        if (flags & 1) x = gelu_f(x);
        const long long o = cOff + (long long)row * ldC + col;
        if (flags & 4) C32[o] = x;
        if (flags & 8) C16[o] = f2b(x);
      }
    }
  }
}

// ---------------------------------------------------------------------------
// Weight transpose+convert: src (K x N) f32  ->  dst (N x K) bf16. Dims %32==0.
// ---------------------------------------------------------------------------
#define MAXW 20
struct WPack {
  const float* src[MAXW];
  u16* dst[MAXW];
  int K[MAXW], N[MAXW];
  int tilePrefix[MAXW + 1];
  int nm;
};

__global__ __launch_bounds__(256) void wtrans_kernel(WPack p) {
  int bid = blockIdx.x;
  int m = 0;
  while (m < p.nm && bid >= p.tilePrefix[m + 1]) ++m;
  if (m >= p.nm) return;
  const int lt = bid - p.tilePrefix[m];
  const int K = p.K[m], N = p.N[m];
  const int tN = N >> 5;
  const int kt = lt / tN, nt = lt - kt * tN;
  const int k0 = kt << 5, n0 = nt << 5;
  const float* src = p.src[m];
  u16* dst = p.dst[m];
  __shared__ float tile[32][33];
  const int t = threadIdx.x;
  const int r = t >> 3, c4 = (t & 7) << 2;
  float4 v = *(const float4*)&src[(size_t)(k0 + r) * N + n0 + c4];
  tile[r][c4 + 0] = v.x; tile[r][c4 + 1] = v.y; tile[r][c4 + 2] = v.z; tile[r][c4 + 3] = v.w;
  __syncthreads();
  u16 o0 = f2b(tile[c4 + 0][r]);
  u16 o1 = f2b(tile[c4 + 1][r]);
  u16 o2 = f2b(tile[c4 + 2][r]);
  u16 o3 = f2b(tile[c4 + 3][r]);
  u64 w = (u64)o0 | ((u64)o1 << 16) | ((u64)o2 << 32) | ((u64)o3 << 48);
  *(u64*)&dst[(size_t)(n0 + r) * K + k0 + c4] = w;
}

// ---------------------------------------------------------------------------
// LayerNorm over D=1024; rows [0,rowsMem) from Xmem, rest from Xout. bf16 out.
// ---------------------------------------------------------------------------
__global__ __launch_bounds__(256) void ln_kernel(
    const float* __restrict__ Xmem, const float* __restrict__ Xout, int rowsMem,
    const float* __restrict__ sc, const float* __restrict__ bi, u16* __restrict__ dst)
{
  const int row = blockIdx.x;
  const float* src = (row < rowsMem) ? (Xmem + (long long)row * 1024)
                                     : (Xout + (long long)(row - rowsMem) * 1024);
  const int t = threadIdx.x;
  float4 v = *(const float4*)&src[t * 4];
  float s1 = v.x + v.y + v.z + v.w;
  float s2 = v.x * v.x + v.y * v.y + v.z * v.z + v.w * v.w;
#pragma unroll
  for (int o = 32; o > 0; o >>= 1) { s1 += __shfl_down(s1, o); s2 += __shfl_down(s2, o); }
  __shared__ float red[8];
  const int wv = t >> 6;
  if ((t & 63) == 0) { red[wv * 2] = s1; red[wv * 2 + 1] = s2; }
  __syncthreads();
  s1 = red[0] + red[2] + red[4] + red[6];
  s2 = red[1] + red[3] + red[5] + red[7];
  const float mu = s1 * (1.f / 1024.f);
  const float var = s2 * (1.f / 1024.f) - mu * mu;
  const float rs = rsqrtf(var + 1e-5f);
  float vals[4] = {v.x, v.y, v.z, v.w};
  u16 o4[4];
#pragma unroll
  for (int j = 0; j < 4; ++j) {
    const int c = t * 4 + j;
    o4[j] = f2b((vals[j] - mu) * rs * sc[c] + bi[c]);
  }
  *(u64*)&dst[(long long)row * 1024 + t * 4] =
      (u64)o4[0] | ((u64)o4[1] << 16) | ((u64)o4[2] << 32) | ((u64)o4[3] << 48);
}

// ---------------------------------------------------------------------------
// Softmax with rel-shift combine. logits = (SC[i][j] + POS[i][j-i+511])*0.125
// for j<=i+512, else masked. Writes probs bf16 IN PLACE over SC row start.
// ---------------------------------------------------------------------------
__global__ __launch_bounds__(256) void softmax_kernel(float* __restrict__ SC,
                                                      const float* __restrict__ POS)
{
  const int i = blockIdx.x;
  const int z = blockIdx.y;
  float* sc = SC + ((long long)z * 512 + i) * 1024;
  const float* ps = POS + ((long long)z * 512 + i) * 1024;
  const int t = threadIdx.x;
  const int jmax = i + 512;
  float4 c4 = *(const float4*)&sc[t * 4];
  float cv[4] = {c4.x, c4.y, c4.z, c4.w};
  float l[4];
#pragma unroll
  for (int j = 0; j < 4; ++j) {
    const int jj = t * 4 + j;
    l[j] = (jj <= jmax) ? (cv[j] + ps[jj - i + 511]) * 0.125f : -1e30f;
  }
  float mx = fmaxf(fmaxf(l[0], l[1]), fmaxf(l[2], l[3]));
#pragma unroll
  for (int o = 32; o > 0; o >>= 1) mx = fmaxf(mx, __shfl_down(mx, o));
  __shared__ float red[8];
  const int wv = t >> 6;
  if ((t & 63) == 0) red[wv] = mx;
  __syncthreads();
  mx = fmaxf(fmaxf(red[0], red[1]), fmaxf(red[2], red[3]));
  float e[4], s = 0.f;
#pragma unroll
  for (int j = 0; j < 4; ++j) { e[j] = expf(l[j] - mx); s += e[j]; }
#pragma unroll
  for (int o = 32; o > 0; o >>= 1) s += __shfl_down(s, o);
  if ((t & 63) == 0) red[4 + wv] = s;
  __syncthreads();
  s = red[4] + red[5] + red[6] + red[7];
  const float inv = 1.f / s;
  u16 o4[4];
#pragma unroll
  for (int j = 0; j < 4; ++j) o4[j] = f2b(e[j] * inv);
  *(u64*)((u16*)sc + t * 4) =
      (u64)o4[0] | ((u64)o4[1] << 16) | ((u64)o4[2] << 32) | ((u64)o4[3] << 48);
}

// ---------------------------------------------------------------------------
// small prep / elementwise kernels
// ---------------------------------------------------------------------------
__global__ __launch_bounds__(256) void prep_quv(const float* __restrict__ Qf,
                                                const float* __restrict__ u,
                                                const float* __restrict__ vb,
                                                u16* __restrict__ QU, u16* __restrict__ QV)
{
  const long long idx = (long long)blockIdx.x * 256 + threadIdx.x;  // B*H*S*64
  const int d2 = idx & 63;
  const int s = (idx >> 6) & 511;
  const int h = (idx >> 15) & 15;
  const int b = (int)(idx >> 19);
  const float q = Qf[(((long long)s * 8 + b) << 10) + h * 64 + d2];
  QU[idx] = f2b(q + u[h * 64 + d2]);
  QV[idx] = f2b(q + vb[h * 64 + d2]);
}

__global__ __launch_bounds__(256) void prep_k(const float* __restrict__ Kf, u16* __restrict__ KBH)
{
  const long long idx = (long long)blockIdx.x * 256 + threadIdx.x;  // B*H*F*64
  const int d2 = idx & 63;
  const int f = (idx >> 6) & 1023;
  const int h = (idx >> 16) & 15;
  const int b = (int)(idx >> 20);
  KBH[idx] = f2b(Kf[(((long long)f * 8 + b) << 10) + h * 64 + d2]);
}

__global__ __launch_bounds__(256) void prep_vt(const float* __restrict__ Vf, u16* __restrict__ VT)
{
  const int f0 = blockIdx.x * 64;
  const int bh = blockIdx.y;
  const int b = bh >> 4, h = bh & 15;
  __shared__ u16 tl[64 * 64];
  const int t = threadIdx.x;
  {
    const int fr = t >> 2, c0 = (t & 3) * 16;
#pragma unroll
    for (int j = 0; j < 16; j += 4) {
      float4 v = *(const float4*)&Vf[(((long long)(f0 + fr) * 8 + b) << 10) + h * 64 + c0 + j];
      tl[fr * 64 + c0 + j + 0] = f2b(v.x);
      tl[fr * 64 + c0 + j + 1] = f2b(v.y);
      tl[fr * 64 + c0 + j + 2] = f2b(v.z);
      tl[fr * 64 + c0 + j + 3] = f2b(v.w);
    }
  }
  __syncthreads();
  {
    const int dr = t >> 2, c0 = (t & 3) * 16;
    u16* dst = VT + ((long long)bh * 64 + dr) * 1024 + f0 + c0;
#pragma unroll
    for (int j = 0; j < 16; ++j) dst[j] = tl[(c0 + j) * 64 + dr];
  }
}

__global__ __launch_bounds__(256) void prep_rh(const float* __restrict__ Rf, u16* __restrict__ RH)
{
  const long long idx = (long long)blockIdx.x * 256 + threadIdx.x;  // H*F*64
  const int d2 = idx & 63;
  const int tt = (idx >> 6) & 1023;
  const int h = (int)(idx >> 16);
  RH[idx] = f2b(Rf[((long long)tt << 10) + h * 64 + d2]);
}

__global__ __launch_bounds__(256) void pe_kernel(u16* __restrict__ PEB)
{
  const long long idx = (long long)blockIdx.x * 256 + threadIdx.x;  // F*D
  const int p = (int)(idx >> 10);
  const int d = idx & 1023;
  const int q = d & 511;
  const float inv = powf(10000.f, -(float)(2 * q) * (1.f / 1024.f));
  const float ang = (float)(1023 - p) * inv;
  PEB[idx] = f2b((d < 512) ? sinf(ang) : cosf(ang));
}

__global__ __launch_bounds__(256) void embed_conv(const float* __restrict__ h, u16* __restrict__ A)
{
  const long long idx = (long long)blockIdx.x * 256 + threadIdx.x;  // SB*IN
  const int c = idx & 127;
  const int r = (int)(idx >> 7);
  const int s = r >> 3, b = r & 7;
  A[idx] = f2b(h[(((long long)b * 512 + s) << 7) + c]);
}

__global__ __launch_bounds__(256) void gru_elemA(const float* __restrict__ T1, float* __restrict__ T2,
                                                 const float* __restrict__ X, u16* __restrict__ RXBF)
{
  const long long i4 = ((long long)blockIdx.x * 256 + threadIdx.x) * 4;  // SB*D
  const int row = (int)(i4 >> 10);
  const int c = i4 & 1023;
  const float* t1 = T1 + (long long)row * 3072 + c;
  float* t2 = T2 + (long long)row * 2048 + c;
  float4 ry = *(const float4*)t1;
  float4 zy = *(const float4*)(t1 + 1024);
  float4 rx = *(const float4*)t2;
  float4 zx = *(const float4*)(t2 + 1024);
  float4 x = *(const float4*)(X + i4);
  float rr[4], zz[4];
  rr[0] = sigm_f(ry.x + rx.x); rr[1] = sigm_f(ry.y + rx.y);
  rr[2] = sigm_f(ry.z + rx.z); rr[3] = sigm_f(ry.w + rx.w);
  zz[0] = sigm_f(zy.x + zx.x - 2.f); zz[1] = sigm_f(zy.y + zx.y - 2.f);
  zz[2] = sigm_f(zy.z + zx.z - 2.f); zz[3] = sigm_f(zy.w + zx.w - 2.f);
  u16 o4[4];
  o4[0] = f2b(rr[0] * x.x); o4[1] = f2b(rr[1] * x.y);
  o4[2] = f2b(rr[2] * x.z); o4[3] = f2b(rr[3] * x.w);
  *(u64*)&RXBF[i4] = (u64)o4[0] | ((u64)o4[1] << 16) | ((u64)o4[2] << 32) | ((u64)o4[3] << 48);
  float4 zo; zo.x = zz[0]; zo.y = zz[1]; zo.z = zz[2]; zo.w = zz[3];
  *(float4*)t2 = zo;
}

__global__ __launch_bounds__(256) void gru_elemB(const float* __restrict__ T1, const float* __restrict__ T2,
                                                 const float* __restrict__ TG, const float* __restrict__ X,
                                                 float* __restrict__ O, u16* __restrict__ XBF)
{
  const long long i4 = ((long long)blockIdx.x * 256 + threadIdx.x) * 4;
  const int row = (int)(i4 >> 10);
  const int c = i4 & 1023;
  float4 gy = *(const float4*)(T1 + (long long)row * 3072 + 2048 + c);
  float4 tt = *(const float4*)(TG + i4);
  float4 z = *(const float4*)(T2 + (long long)row * 2048 + c);
  float4 x = *(const float4*)(X + i4);
  float4 o;
  o.x = (1.f - z.x) * x.x + z.x * tanhf(gy.x + tt.x);
  o.y = (1.f - z.y) * x.y + z.y * tanhf(gy.y + tt.y);
  o.z = (1.f - z.z) * x.z + z.z * tanhf(gy.z + tt.z);
  o.w = (1.f - z.w) * x.w + z.w * tanhf(gy.w + tt.w);
  *(float4*)(O + i4) = o;
  u16 o4[4];
  o4[0] = f2b(o.x); o4[1] = f2b(o.y); o4[2] = f2b(o.z); o4[3] = f2b(o.w);
  *(u64*)&XBF[i4] = (u64)o4[0] | ((u64)o4[1] << 16) | ((u64)o4[2] << 32) | ((u64)o4[3] << 48);
}

__global__ __launch_bounds__(256) void out_transpose(const float* __restrict__ O, float* __restrict__ dst)
{
  const long long i4 = ((long long)blockIdx.x * 256 + threadIdx.x) * 4;
  const int d = i4 & 1023;
  const int r = (int)(i4 >> 10);
  const int s = r >> 3, b = r & 7;
  float4 v = *(const float4*)(O + i4);
  *(float4*)&dst[(((long long)b * 512 + s) << 10) + d] = v;
}

// ---------------------------------------------------------------------------
extern "C" void kernel_launch(void* const* d_in, const int* in_sizes, int n_in,
                              void* d_out, int out_size, void* d_ws, size_t ws_size,
                              hipStream_t stream)
{
  (void)in_sizes; (void)n_in; (void)out_size;
  const float* h_in   = (const float*)d_in[0];
  const float* memory = (const float*)d_in[1];
  const float* We     = (const float*)d_in[2];
  const float* be     = (const float*)d_in[3];
  const float* ln1s   = (const float*)d_in[4];
  const float* ln1b   = (const float*)d_in[5];
  const float* ln2s   = (const float*)d_in[6];
  const float* ln2b   = (const float*)d_in[7];
  const float* Wq     = (const float*)d_in[8];
  const float* bq     = (const float*)d_in[9];
  const float* Wk     = (const float*)d_in[10];
  const float* bk     = (const float*)d_in[11];
  const float* Wv     = (const float*)d_in[12];
  const float* bv     = (const float*)d_in[13];
  const float* Wr     = (const float*)d_in[14];
  const float* br     = (const float*)d_in[15];
  const float* Wo     = (const float*)d_in[16];
  const float* bo     = (const float*)d_in[17];
  const float* uu     = (const float*)d_in[18];
  const float* vbp    = (const float*)d_in[19];
  const float* gWr    = (const float*)d_in[20];
  const float* gUr    = (const float*)d_in[21];
  const float* gWz    = (const float*)d_in[22];
  const float* gUz    = (const float*)d_in[23];
  const float* gWg    = (const float*)d_in[24];
  const float* gUg    = (const float*)d_in[25];
  const float* fW1    = (const float*)d_in[26];
  const float* fb1    = (const float*)d_in[27];
  const float* fW2    = (const float*)d_in[28];
  const float* fb2    = (const float*)d_in[29];

  constexpr int S = 512, MM = 512, B = 8, D = 1024, H = 16, IN = 128, F = 1024;
  constexpr int SB = 4096, FB = 8192;
  constexpr long long DD = (long long)D * D;

  char* ws = (char*)d_ws;
  size_t off = 0;
  auto alloc = [&](size_t bytes) -> size_t {
    size_t o = off; off = (off + bytes + 255) & ~(size_t)255; return o;
  };
  const size_t oWT   = alloc((size_t)25 * DD * 2);
  const size_t oWET  = alloc((size_t)D * IN * 2);
  const size_t oPEB  = alloc((size_t)F * D * 2);
  const size_t oOUT  = alloc((size_t)SB * D * 4);
  const size_t oOUT1 = alloc((size_t)SB * D * 4);
  const size_t oXBF  = alloc((size_t)SB * D * 2);
  const size_t oYBF  = alloc((size_t)SB * D * 2);
  const size_t oYBFA = alloc((size_t)SB * D * 2);
  const size_t oABUF = alloc((size_t)SB * D * 2);
  const size_t oKN   = alloc((size_t)FB * D * 2);
  const size_t oQU   = alloc((size_t)B * H * S * 64 * 2);
  const size_t oQV   = alloc((size_t)B * H * S * 64 * 2);
  const size_t oKBH  = alloc((size_t)B * H * F * 64 * 2);
  const size_t oVT   = alloc((size_t)B * H * F * 64 * 2);
  const size_t oRH   = alloc((size_t)H * F * 64 * 2);
  const size_t oUNI  = off;

  const size_t tmpBytes = (size_t)SB * D * 4 * 6;  // T1(3D)+T2(2D)+TG(1D)
  int Bc = 2;
  {
    size_t scB = (size_t)Bc * H * S * F * 4;
    size_t need = oUNI + (2 * scB > tmpBytes ? 2 * scB : tmpBytes);
    if (need > ws_size) Bc = 1;
  }
  const size_t scBytes = (size_t)Bc * H * S * F * 4;

  u16* WTp   = (u16*)(ws + oWT);
  u16* WETp  = (u16*)(ws + oWET);
  u16* PEBp  = (u16*)(ws + oPEB);
  float* OUTp  = (float*)(ws + oOUT);
  float* OUT1p = (float*)(ws + oOUT1);
  u16* XBFp  = (u16*)(ws + oXBF);
  u16* YBFp  = (u16*)(ws + oYBF);
  u16* YBFAp = (u16*)(ws + oYBFA);
  u16* ABUFp = (u16*)(ws + oABUF);
  u16* KNp   = (u16*)(ws + oKN);
  u16* QUp   = (u16*)(ws + oQU);
  u16* QVp   = (u16*)(ws + oQV);
  u16* KBHp  = (u16*)(ws + oKBH);
  u16* VTp   = (u16*)(ws + oVT);
  u16* RHp   = (u16*)(ws + oRH);
  float* Qf   = (float*)(ws + oUNI);
  float* SCp  = (float*)(ws + oUNI);
  float* POSp = (float*)(ws + oUNI + scBytes);
  float* T1   = (float*)(ws + oUNI);
  float* T2   = (float*)(ws + oUNI + (size_t)SB * 3 * D * 4);
  float* TGp  = (float*)(ws + oUNI + (size_t)SB * 5 * D * 4);
  u16* FFNBp  = (u16*)(ws + oUNI);

  auto gemm = [&](const u16* A, const u16* Bt, const float* bias, float* C32, u16* C16,
                  int M, int N, int K, int ldA, int ldB, int ldC,
                  long long sA, long long sBb, long long sBh, long long sC, int nH, int Z,
                  int flags) {
    dim3 grid((M + 127) / 128, (N + 127) / 128, Z);
    gemm_bt<<<grid, 256, 0, stream>>>(A, Bt, bias, C32, C16, M, N, K, ldA, ldB, ldC,
                                      sA, sBb, sBh, sC, nH, flags);
  };

  // positional encodings (bf16) + We^T
  pe_kernel<<<(F * D) / 256, 256, 0, stream>>>(PEBp);
  {
    WPack p{};
    p.nm = 1; p.src[0] = We; p.dst[0] = WETp; p.K[0] = IN; p.N[0] = D;
    p.tilePrefix[0] = 0; p.tilePrefix[1] = (IN / 32) * (D / 32);
    wtrans_kernel<<<p.tilePrefix[1], 256, 0, stream>>>(p);
  }
  // embed: x = gelu(h^T @ We + be)
  embed_conv<<<(SB * IN) / 256, 256, 0, stream>>>(h_in, ABUFp);
  gemm(ABUFp, WETp, be, OUTp, XBFp, SB, D, IN, IN, IN, D, 0, 0, 0, 0, 1, 1, 1 | 2 | 4 | 8);

  for (int li = 0; li < 4; ++li) {
    // ---- transpose this layer's weights to (N x K) bf16 ----
    WPack p{};
    int nt = 0, id = 0;
    auto addw = [&](const float* s, u16* d, int K, int N) {
      p.src[id] = s; p.dst[id] = d; p.K[id] = K; p.N[id] = N;
      p.tilePrefix[id] = nt; nt += (K / 32) * (N / 32); ++id;
    };
    addw(Wq + li * DD, WTp + 0 * DD, D, D);
    addw(Wk + li * DD, WTp + 1 * DD, D, D);
    addw(Wv + li * DD, WTp + 2 * DD, D, D);
    addw(Wr + li * DD, WTp + 3 * DD, D, D);
    addw(Wo + li * DD, WTp + 4 * DD, D, D);
    addw(gWr + (li * 2 + 0) * DD, WTp + 5 * DD, D, D);
    addw(gWz + (li * 2 + 0) * DD, WTp + 6 * DD, D, D);
    addw(gWg + (li * 2 + 0) * DD, WTp + 7 * DD, D, D);
    addw(gUr + (li * 2 + 0) * DD, WTp + 8 * DD, D, D);
    addw(gUz + (li * 2 + 0) * DD, WTp + 9 * DD, D, D);
    addw(gUg + (li * 2 + 0) * DD, WTp + 10 * DD, D, D);
    addw(gWr + (li * 2 + 1) * DD, WTp + 11 * DD, D, D);
    addw(gWz + (li * 2 + 1) * DD, WTp + 12 * DD, D, D);
    addw(gWg + (li * 2 + 1) * DD, WTp + 13 * DD, D, D);
    addw(gUr + (li * 2 + 1) * DD, WTp + 14 * DD, D, D);
    addw(gUz + (li * 2 + 1) * DD, WTp + 15 * DD, D, D);
    addw(gUg + (li * 2 + 1) * DD, WTp + 16 * DD, D, D);
    addw(fW1 + li * (long long)D * 4096, WTp + 17 * DD, D, 4096);
    addw(fW2 + li * (long long)4096 * D, WTp + 21 * DD, 4096, D);
    p.tilePrefix[id] = nt; p.nm = id;
    wtrans_kernel<<<nt, 256, 0, stream>>>(p);

    // ---- LN of [memory; out] -> KN (rows f*B+b); QN = rows [MB..) ----
    ln_kernel<<<FB, 256, 0, stream>>>(memory + (long long)li * MM * B * D, OUTp, MM * B,
                                      ln1s + li * D, ln1b + li * D, KNp);
    const u16* QN = KNp + (size_t)MM * B * D;

    // ---- projections ----
    gemm(QN, WTp + 0 * DD, bq + li * D, Qf, nullptr, SB, D, D, D, D, D, 0, 0, 0, 0, 1, 1, 2 | 4);
    prep_quv<<<(B * H * S * 64) / 256, 256, 0, stream>>>(Qf, uu + li * H * 64, vbp + li * H * 64, QUp, QVp);
    gemm(KNp, WTp + 1 * DD, bk + li * D, Qf, nullptr, FB, D, D, D, D, D, 0, 0, 0, 0, 1, 1, 2 | 4);
    prep_k<<<(B * H * F * 64) / 256, 256, 0, stream>>>(Qf, KBHp);
    gemm(KNp, WTp + 2 * DD, bv + li * D, Qf, nullptr, FB, D, D, D, D, D, 0, 0, 0, 0, 1, 1, 2 | 4);
    prep_vt<<<dim3(F / 64, B * H), 256, 0, stream>>>(Qf, VTp);
    gemm(PEBp, WTp + 3 * DD, br + li * D, Qf, nullptr, F, D, D, D, D, D, 0, 0, 0, 0, 1, 1, 2 | 4);
    prep_rh<<<(H * F * 64) / 256, 256, 0, stream>>>(Qf, RHp);

    // ---- attention, chunked over batch ----
    for (int bc0 = 0; bc0 < B; bc0 += Bc) {
      const int Z = Bc * H;
      gemm(QUp + (size_t)bc0 * H * S * 64, KBHp + (size_t)bc0 * H * F * 64, nullptr, SCp, nullptr,
           S, F, 64, 64, 64, F,
           (long long)S * 64, (long long)H * F * 64, (long long)F * 64, (long long)S * F, H, Z, 4);
      gemm(QVp + (size_t)bc0 * H * S * 64, RHp, nullptr, POSp, nullptr,
           S, F, 64, 64, 64, F,
           (long long)S * 64, 0, (long long)F * 64, (long long)S * F, H, Z, 4);
      softmax_kernel<<<dim3(S, Z), 256, 0, stream>>>(SCp, POSp);
      gemm((const u16*)SCp, VTp + (size_t)bc0 * H * 64 * F, nullptr, nullptr,
           YBFAp + (size_t)bc0 * D,
           S, 64, F, 2 * F, F, B * D,
           (long long)S * F * 2, (long long)H * 64 * F, (long long)64 * F, 64, H, Z, 8);
    }

    // ---- output projection: y = gelu(attn @ Wo + bo) (bf16) ----
    gemm(YBFAp, WTp + 4 * DD, bo + li * D, nullptr, YBFp, SB, D, D, D, D, D, 0, 0, 0, 0, 1, 1, 1 | 2 | 8);

    // ---- GRU1: out1 = gru(out, y) ----
    gemm(YBFp, WTp + 5 * DD, nullptr, T1, nullptr, SB, 3 * D, D, D, D, 3 * D, 0, 0, 0, 0, 1, 1, 4);
    gemm(XBFp, WTp + 8 * DD, nullptr, T2, nullptr, SB, 2 * D, D, D, D, 2 * D, 0, 0, 0, 0, 1, 1, 4);
    gru_elemA<<<(SB * D / 4) / 256, 256, 0, stream>>>(T1, T2, OUTp, ABUFp);
    gemm(ABUFp, WTp + 10 * DD, nullptr, TGp, nullptr, SB, D, D, D, D, D, 0, 0, 0, 0, 1, 1, 4);
    gru_elemB<<<(SB * D / 4) / 256, 256, 0, stream>>>(T1, T2, TGp, OUTp, OUT1p, XBFp);

    // ---- FFN ----
    ln_kernel<<<SB, 256, 0, stream>>>(OUT1p, OUT1p, SB, ln2s + li * D, ln2b + li * D, ABUFp);
    gemm(ABUFp, WTp + 17 * DD, fb1 + li * 4096, nullptr, FFNBp, SB, 4096, D, D, D, 4096,
         0, 0, 0, 0, 1, 1, 1 | 2 | 8);
    gemm(FFNBp, WTp + 21 * DD, fb2 + li * D, nullptr, YBFp, SB, D, 4096, 4096, 4096, D,
         0, 0, 0, 0, 1, 1, 1 | 2 | 8);

    // ---- GRU2: out = gru(out1, e3) ----
    gemm(YBFp, WTp + 11 * DD, nullptr, T1, nullptr, SB, 3 * D, D, D, D, 3 * D, 0, 0, 0, 0, 1, 1, 4);
    gemm(XBFp, WTp + 14 * DD, nullptr, T2, nullptr, SB, 2 * D, D, D, D, 2 * D, 0, 0, 0, 0, 1, 1, 4);
    gru_elemA<<<(SB * D / 4) / 256, 256, 0, stream>>>(T1, T2, OUT1p, ABUFp);
    gemm(ABUFp, WTp + 16 * DD, nullptr, TGp, nullptr, SB, D, D, D, D, D, 0, 0, 0, 0, 1, 1, 4);
    gru_elemB<<<(SB * D / 4) / 256, 256, 0, stream>>>(T1, T2, TGp, OUT1p, OUTp, XBFp);
  }

  out_transpose<<<(SB * D / 4) / 256, 256, 0, stream>>>(OUTp, (float*)d_out);
}

// Round 2
// 4871.532 us; speedup vs baseline: 1.1210x; 1.1210x over previous
//
#include <hip/hip_runtime.h>

typedef unsigned short u16;
typedef unsigned long long u64;
typedef __attribute__((ext_vector_type(8))) short bf16x8;
typedef __attribute__((ext_vector_type(4))) float f32x4;

#define DEVI __device__ __forceinline__

DEVI u16 f2b(float f) {
  unsigned u = __float_as_uint(f);
  u += 0x7fffu + ((u >> 16) & 1u);
  return (u16)(u >> 16);
}
DEVI float gelu_f(float x) { return 0.5f * x * (1.f + erff(x * 0.70710678118654752f)); }
DEVI float sigm_f(float x) { return 1.f / (1.f + expf(-x)); }

DEVI void gload16(const void* g, void* l) {
  __builtin_amdgcn_global_load_lds((__attribute__((address_space(1))) void*)g,
                                   (__attribute__((address_space(3))) void*)l, 16, 0, 0);
}

// ---------------------------------------------------------------------------
// Generic batched GEMM:  C[z] = act(A[z] (MxK) @ Bt[z]^T + bias), Bt is (N x K).
// flags: 1=gelu, 2=bias, 4=store f32, 8=store bf16
// batch offsets: A += z*sA ; Bt += (z/nH)*sBb + (z%nH)*sBh ; C += z*sC
// Requires K % 64 == 0. M,N bounds handled (clamped stage + guarded store).
// T3-minimum 2-phase pipeline: double-buffered LDS, stage(t+1) issued before
// compute(t), single __syncthreads (vmcnt(0)+barrier drain) per K-step.
// ---------------------------------------------------------------------------
__global__ __launch_bounds__(256) void gemm_bt(
    const u16* __restrict__ A, const u16* __restrict__ Bt,
    const float* __restrict__ bias, float* __restrict__ C32, u16* __restrict__ C16,
    int M, int N, int K, int ldA, int ldB, int ldC,
    long long sA, long long sBb, long long sBh, long long sC, int nH, int flags)
{
  __shared__ __align__(16) u16 Sm[2][256 * 64];   // [buf][A(128x64) | B(128x64)]
  const int z = blockIdx.z;
  const int zb = z / nH, zh = z - zb * nH;
  A  += (long long)z * sA;
  Bt += (long long)zb * sBb + (long long)zh * sBh;
  const long long cOff = (long long)z * sC;
  const int m0 = blockIdx.x * 128, n0 = blockIdx.y * 128;
  const int t = threadIdx.x, lane = t & 63;
  const int wm = ((t >> 7) & 1) * 64, wn = ((t >> 6) & 1) * 64;

  f32x4 acc[4][4];
#pragma unroll
  for (int i = 0; i < 4; ++i)
#pragma unroll
    for (int j = 0; j < 4; ++j) { f32x4 zz = {0.f, 0.f, 0.f, 0.f}; acc[i][j] = zz; }

  auto stage = [&](int buf, int k0) {
#pragma unroll
    for (int r = 0; r < 4; ++r) {
      const int c = r * 256 + t;
      const int row = c >> 3;
      const int col = (c & 7) << 3;
      int ga = m0 + row; if (ga >= M) ga = M - 1;
      gload16(A + (long long)ga * ldA + (k0 + col),
              &Sm[buf][(size_t)(r * 256 + (t & 192)) * 8]);
      int gb = n0 + row; if (gb >= N) gb = N - 1;
      gload16(Bt + (long long)gb * ldB + (k0 + col),
              &Sm[buf][(size_t)(1024 + r * 256 + (t & 192)) * 8]);
    }
  };

  auto compute = [&](int buf) {
    const u16* As = &Sm[buf][0];
    const u16* Bs = &Sm[buf][128 * 64];
#pragma unroll
    for (int ks = 0; ks < 2; ++ks) {
      const int ko = ks * 32 + ((lane >> 4) << 3);
      bf16x8 af[4], bfv[4];
#pragma unroll
      for (int i = 0; i < 4; ++i)
        af[i] = *(const bf16x8*)&As[(wm + i * 16 + (lane & 15)) * 64 + ko];
#pragma unroll
      for (int i = 0; i < 4; ++i)
        bfv[i] = *(const bf16x8*)&Bs[(wn + i * 16 + (lane & 15)) * 64 + ko];
#pragma unroll
      for (int mi = 0; mi < 4; ++mi)
#pragma unroll
        for (int ni = 0; ni < 4; ++ni)
          acc[mi][ni] = __builtin_amdgcn_mfma_f32_16x16x32_bf16(af[mi], bfv[ni], acc[mi][ni], 0, 0, 0);
    }
  };

  // prologue
  stage(0, 0);
  __syncthreads();
  int cur = 0;
  for (int k0 = 64; k0 < K; k0 += 64) {
    stage(cur ^ 1, k0);        // issue next-tile loads (stay in flight over compute)
    compute(cur);              // ds_read + MFMA on current buffer
    __syncthreads();           // single vmcnt(0)+lgkmcnt(0)+barrier per K-step
    cur ^= 1;
  }
  compute(cur);                // last tile, no prefetch

  const int cb = n0 + wn + (lane & 15);
  const int rb = m0 + wm + ((lane >> 4) << 2);
#pragma unroll
  for (int ni = 0; ni < 4; ++ni) {
    const int col = cb + ni * 16;
    if (col >= N) continue;
    const float bv = (flags & 2) ? bias[col] : 0.f;
#pragma unroll
    for (int mi = 0; mi < 4; ++mi) {
#pragma unroll
      for (int q = 0; q < 4; ++q) {
        const int row = rb + mi * 16 + q;
        if (row >= M) continue;
        float x = acc[mi][ni][q] + bv;
        if (flags & 1) x = gelu_f(x);
        const long long o = cOff + (long long)row * ldC + col;
        if (flags & 4) C32[o] = x;
        if (flags & 8) C16[o] = f2b(x);
      }
    }
  }
}

// ---------------------------------------------------------------------------
// Weight transpose+convert: src (K x N) f32  ->  dst (N x K) bf16. Dims %32==0.
// ---------------------------------------------------------------------------
#define MAXW 20
struct WPack {
  const float* src[MAXW];
  u16* dst[MAXW];
  int K[MAXW], N[MAXW];
  int tilePrefix[MAXW + 1];
  int nm;
};

__global__ __launch_bounds__(256) void wtrans_kernel(WPack p) {
  int bid = blockIdx.x;
  int m = 0;
  while (m < p.nm && bid >= p.tilePrefix[m + 1]) ++m;
  if (m >= p.nm) return;
  const int lt = bid - p.tilePrefix[m];
  const int K = p.K[m], N = p.N[m];
  const int tN = N >> 5;
  const int kt = lt / tN, nt = lt - kt * tN;
  const int k0 = kt << 5, n0 = nt << 5;
  const float* src = p.src[m];
  u16* dst = p.dst[m];
  __shared__ float tile[32][33];
  const int t = threadIdx.x;
  const int r = t >> 3, c4 = (t & 7) << 2;
  float4 v = *(const float4*)&src[(size_t)(k0 + r) * N + n0 + c4];
  tile[r][c4 + 0] = v.x; tile[r][c4 + 1] = v.y; tile[r][c4 + 2] = v.z; tile[r][c4 + 3] = v.w;
  __syncthreads();
  u16 o0 = f2b(tile[c4 + 0][r]);
  u16 o1 = f2b(tile[c4 + 1][r]);
  u16 o2 = f2b(tile[c4 + 2][r]);
  u16 o3 = f2b(tile[c4 + 3][r]);
  u64 w = (u64)o0 | ((u64)o1 << 16) | ((u64)o2 << 32) | ((u64)o3 << 48);
  *(u64*)&dst[(size_t)(n0 + r) * K + k0 + c4] = w;
}

// ---------------------------------------------------------------------------
// LayerNorm over D=1024; rows [0,rowsMem) from Xmem, rest from Xout. bf16 out.
// ---------------------------------------------------------------------------
__global__ __launch_bounds__(256) void ln_kernel(
    const float* __restrict__ Xmem, const float* __restrict__ Xout, int rowsMem,
    const float* __restrict__ sc, const float* __restrict__ bi, u16* __restrict__ dst)
{
  const int row = blockIdx.x;
  const float* src = (row < rowsMem) ? (Xmem + (long long)row * 1024)
                                     : (Xout + (long long)(row - rowsMem) * 1024);
  const int t = threadIdx.x;
  float4 v = *(const float4*)&src[t * 4];
  float s1 = v.x + v.y + v.z + v.w;
  float s2 = v.x * v.x + v.y * v.y + v.z * v.z + v.w * v.w;
#pragma unroll
  for (int o = 32; o > 0; o >>= 1) { s1 += __shfl_down(s1, o); s2 += __shfl_down(s2, o); }
  __shared__ float red[8];
  const int wv = t >> 6;
  if ((t & 63) == 0) { red[wv * 2] = s1; red[wv * 2 + 1] = s2; }
  __syncthreads();
  s1 = red[0] + red[2] + red[4] + red[6];
  s2 = red[1] + red[3] + red[5] + red[7];
  const float mu = s1 * (1.f / 1024.f);
  const float var = s2 * (1.f / 1024.f) - mu * mu;
  const float rs = rsqrtf(var + 1e-5f);
  float vals[4] = {v.x, v.y, v.z, v.w};
  u16 o4[4];
#pragma unroll
  for (int j = 0; j < 4; ++j) {
    const int c = t * 4 + j;
    o4[j] = f2b((vals[j] - mu) * rs * sc[c] + bi[c]);
  }
  *(u64*)&dst[(long long)row * 1024 + t * 4] =
      (u64)o4[0] | ((u64)o4[1] << 16) | ((u64)o4[2] << 32) | ((u64)o4[3] << 48);
}

// ---------------------------------------------------------------------------
// Softmax with rel-shift combine. logits = (SC[i][j] + POS[i][j-i+511])*0.125
// for j<=i+512, else masked. Writes probs bf16 IN PLACE over SC row start.
// ---------------------------------------------------------------------------
__global__ __launch_bounds__(256) void softmax_kernel(float* __restrict__ SC,
                                                      const float* __restrict__ POS)
{
  const int i = blockIdx.x;
  const int z = blockIdx.y;
  float* sc = SC + ((long long)z * 512 + i) * 1024;
  const float* ps = POS + ((long long)z * 512 + i) * 1024;
  const int t = threadIdx.x;
  const int jmax = i + 512;
  float4 c4 = *(const float4*)&sc[t * 4];
  float cv[4] = {c4.x, c4.y, c4.z, c4.w};
  float l[4];
#pragma unroll
  for (int j = 0; j < 4; ++j) {
    const int jj = t * 4 + j;
    l[j] = (jj <= jmax) ? (cv[j] + ps[jj - i + 511]) * 0.125f : -1e30f;
  }
  float mx = fmaxf(fmaxf(l[0], l[1]), fmaxf(l[2], l[3]));
#pragma unroll
  for (int o = 32; o > 0; o >>= 1) mx = fmaxf(mx, __shfl_down(mx, o));
  __shared__ float red[8];
  const int wv = t >> 6;
  if ((t & 63) == 0) red[wv] = mx;
  __syncthreads();
  mx = fmaxf(fmaxf(red[0], red[1]), fmaxf(red[2], red[3]));
  float e[4], s = 0.f;
#pragma unroll
  for (int j = 0; j < 4; ++j) { e[j] = expf(l[j] - mx); s += e[j]; }
#pragma unroll
  for (int o = 32; o > 0; o >>= 1) s += __shfl_down(s, o);
  if ((t & 63) == 0) red[4 + wv] = s;
  __syncthreads();
  s = red[4] + red[5] + red[6] + red[7];
  const float inv = 1.f / s;
  u16 o4[4];
#pragma unroll
  for (int j = 0; j < 4; ++j) o4[j] = f2b(e[j] * inv);
  *(u64*)((u16*)sc + t * 4) =
      (u64)o4[0] | ((u64)o4[1] << 16) | ((u64)o4[2] << 32) | ((u64)o4[3] << 48);
}

// ---------------------------------------------------------------------------
// small prep / elementwise kernels
// ---------------------------------------------------------------------------
__global__ __launch_bounds__(256) void prep_quv(const float* __restrict__ Qf,
                                                const float* __restrict__ u,
                                                const float* __restrict__ vb,
                                                u16* __restrict__ QU, u16* __restrict__ QV)
{
  const long long idx = (long long)blockIdx.x * 256 + threadIdx.x;  // B*H*S*64
  const int d2 = idx & 63;
  const int s = (idx >> 6) & 511;
  const int h = (idx >> 15) & 15;
  const int b = (int)(idx >> 19);
  const float q = Qf[(((long long)s * 8 + b) << 10) + h * 64 + d2];
  QU[idx] = f2b(q + u[h * 64 + d2]);
  QV[idx] = f2b(q + vb[h * 64 + d2]);
}

__global__ __launch_bounds__(256) void prep_k(const float* __restrict__ Kf, u16* __restrict__ KBH)
{
  const long long idx = (long long)blockIdx.x * 256 + threadIdx.x;  // B*H*F*64
  const int d2 = idx & 63;
  const int f = (idx >> 6) & 1023;
  const int h = (idx >> 16) & 15;
  const int b = (int)(idx >> 20);
  KBH[idx] = f2b(Kf[(((long long)f * 8 + b) << 10) + h * 64 + d2]);
}

__global__ __launch_bounds__(256) void prep_vt(const float* __restrict__ Vf, u16* __restrict__ VT)
{
  const int f0 = blockIdx.x * 64;
  const int bh = blockIdx.y;
  const int b = bh >> 4, h = bh & 15;
  __shared__ u16 tl[64 * 64];
  const int t = threadIdx.x;
  {
    const int fr = t >> 2, c0 = (t & 3) * 16;
#pragma unroll
    for (int j = 0; j < 16; j += 4) {
      float4 v = *(const float4*)&Vf[(((long long)(f0 + fr) * 8 + b) << 10) + h * 64 + c0 + j];
      tl[fr * 64 + c0 + j + 0] = f2b(v.x);
      tl[fr * 64 + c0 + j + 1] = f2b(v.y);
      tl[fr * 64 + c0 + j + 2] = f2b(v.z);
      tl[fr * 64 + c0 + j + 3] = f2b(v.w);
    }
  }
  __syncthreads();
  {
    const int dr = t >> 2, c0 = (t & 3) * 16;
    u16* dst = VT + ((long long)bh * 64 + dr) * 1024 + f0 + c0;
#pragma unroll
    for (int j = 0; j < 16; ++j) dst[j] = tl[(c0 + j) * 64 + dr];
  }
}

__global__ __launch_bounds__(256) void prep_rh(const float* __restrict__ Rf, u16* __restrict__ RH)
{
  const long long idx = (long long)blockIdx.x * 256 + threadIdx.x;  // H*F*64
  const int d2 = idx & 63;
  const int tt = (idx >> 6) & 1023;
  const int h = (int)(idx >> 16);
  RH[idx] = f2b(Rf[((long long)tt << 10) + h * 64 + d2]);
}

__global__ __launch_bounds__(256) void pe_kernel(u16* __restrict__ PEB)
{
  const long long idx = (long long)blockIdx.x * 256 + threadIdx.x;  // F*D
  const int p = (int)(idx >> 10);
  const int d = idx & 1023;
  const int q = d & 511;
  const float inv = powf(10000.f, -(float)(2 * q) * (1.f / 1024.f));
  const float ang = (float)(1023 - p) * inv;
  PEB[idx] = f2b((d < 512) ? sinf(ang) : cosf(ang));
}

__global__ __launch_bounds__(256) void embed_conv(const float* __restrict__ h, u16* __restrict__ A)
{
  const long long idx = (long long)blockIdx.x * 256 + threadIdx.x;  // SB*IN
  const int c = idx & 127;
  const int r = (int)(idx >> 7);
  const int s = r >> 3, b = r & 7;
  A[idx] = f2b(h[(((long long)b * 512 + s) << 7) + c]);
}

__global__ __launch_bounds__(256) void gru_elemA(const float* __restrict__ T1, float* __restrict__ T2,
                                                 const float* __restrict__ X, u16* __restrict__ RXBF)
{
  const long long i4 = ((long long)blockIdx.x * 256 + threadIdx.x) * 4;  // SB*D
  const int row = (int)(i4 >> 10);
  const int c = i4 & 1023;
  const float* t1 = T1 + (long long)row * 3072 + c;
  float* t2 = T2 + (long long)row * 2048 + c;
  float4 ry = *(const float4*)t1;
  float4 zy = *(const float4*)(t1 + 1024);
  float4 rx = *(const float4*)t2;
  float4 zx = *(const float4*)(t2 + 1024);
  float4 x = *(const float4*)(X + i4);
  float rr[4], zz[4];
  rr[0] = sigm_f(ry.x + rx.x); rr[1] = sigm_f(ry.y + rx.y);
  rr[2] = sigm_f(ry.z + rx.z); rr[3] = sigm_f(ry.w + rx.w);
  zz[0] = sigm_f(zy.x + zx.x - 2.f); zz[1] = sigm_f(zy.y + zx.y - 2.f);
  zz[2] = sigm_f(zy.z + zx.z - 2.f); zz[3] = sigm_f(zy.w + zx.w - 2.f);
  u16 o4[4];
  o4[0] = f2b(rr[0] * x.x); o4[1] = f2b(rr[1] * x.y);
  o4[2] = f2b(rr[2] * x.z); o4[3] = f2b(rr[3] * x.w);
  *(u64*)&RXBF[i4] = (u64)o4[0] | ((u64)o4[1] << 16) | ((u64)o4[2] << 32) | ((u64)o4[3] << 48);
  float4 zo; zo.x = zz[0]; zo.y = zz[1]; zo.z = zz[2]; zo.w = zz[3];
  *(float4*)t2 = zo;
}

__global__ __launch_bounds__(256) void gru_elemB(const float* __restrict__ T1, const float* __restrict__ T2,
                                                 const float* __restrict__ TG, const float* __restrict__ X,
                                                 float* __restrict__ O, u16* __restrict__ XBF)
{
  const long long i4 = ((long long)blockIdx.x * 256 + threadIdx.x) * 4;
  const int row = (int)(i4 >> 10);
  const int c = i4 & 1023;
  float4 gy = *(const float4*)(T1 + (long long)row * 3072 + 2048 + c);
  float4 tt = *(const float4*)(TG + i4);
  float4 z = *(const float4*)(T2 + (long long)row * 2048 + c);
  float4 x = *(const float4*)(X + i4);
  float4 o;
  o.x = (1.f - z.x) * x.x + z.x * tanhf(gy.x + tt.x);
  o.y = (1.f - z.y) * x.y + z.y * tanhf(gy.y + tt.y);
  o.z = (1.f - z.z) * x.z + z.z * tanhf(gy.z + tt.z);
  o.w = (1.f - z.w) * x.w + z.w * tanhf(gy.w + tt.w);
  *(float4*)(O + i4) = o;
  u16 o4[4];
  o4[0] = f2b(o.x); o4[1] = f2b(o.y); o4[2] = f2b(o.z); o4[3] = f2b(o.w);
  *(u64*)&XBF[i4] = (u64)o4[0] | ((u64)o4[1] << 16) | ((u64)o4[2] << 32) | ((u64)o4[3] << 48);
}

__global__ __launch_bounds__(256) void out_transpose(const float* __restrict__ O, float* __restrict__ dst)
{
  const long long i4 = ((long long)blockIdx.x * 256 + threadIdx.x) * 4;
  const int d = i4 & 1023;
  const int r = (int)(i4 >> 10);
  const int s = r >> 3, b = r & 7;
  float4 v = *(const float4*)(O + i4);
  *(float4*)&dst[(((long long)b * 512 + s) << 10) + d] = v;
}

// ---------------------------------------------------------------------------
extern "C" void kernel_launch(void* const* d_in, const int* in_sizes, int n_in,
                              void* d_out, int out_size, void* d_ws, size_t ws_size,
                              hipStream_t stream)
{
  (void)in_sizes; (void)n_in; (void)out_size;
  const float* h_in   = (const float*)d_in[0];
  const float* memory = (const float*)d_in[1];
  const float* We     = (const float*)d_in[2];
  const float* be     = (const float*)d_in[3];
  const float* ln1s   = (const float*)d_in[4];
  const float* ln1b   = (const float*)d_in[5];
  const float* ln2s   = (const float*)d_in[6];
  const float* ln2b   = (const float*)d_in[7];
  const float* Wq     = (const float*)d_in[8];
  const float* bq     = (const float*)d_in[9];
  const float* Wk     = (const float*)d_in[10];
  const float* bk     = (const float*)d_in[11];
  const float* Wv     = (const float*)d_in[12];
  const float* bv     = (const float*)d_in[13];
  const float* Wr     = (const float*)d_in[14];
  const float* br     = (const float*)d_in[15];
  const float* Wo     = (const float*)d_in[16];
  const float* bo     = (const float*)d_in[17];
  const float* uu     = (const float*)d_in[18];
  const float* vbp    = (const float*)d_in[19];
  const float* gWr    = (const float*)d_in[20];
  const float* gUr    = (const float*)d_in[21];
  const float* gWz    = (const float*)d_in[22];
  const float* gUz    = (const float*)d_in[23];
  const float* gWg    = (const float*)d_in[24];
  const float* gUg    = (const float*)d_in[25];
  const float* fW1    = (const float*)d_in[26];
  const float* fb1    = (const float*)d_in[27];
  const float* fW2    = (const float*)d_in[28];
  const float* fb2    = (const float*)d_in[29];

  constexpr int S = 512, MM = 512, B = 8, D = 1024, H = 16, IN = 128, F = 1024;
  constexpr int SB = 4096, FB = 8192;
  constexpr long long DD = (long long)D * D;

  char* ws = (char*)d_ws;
  size_t off = 0;
  auto alloc = [&](size_t bytes) -> size_t {
    size_t o = off; off = (off + bytes + 255) & ~(size_t)255; return o;
  };
  const size_t oWT   = alloc((size_t)25 * DD * 2);
  const size_t oWET  = alloc((size_t)D * IN * 2);
  const size_t oPEB  = alloc((size_t)F * D * 2);
  const size_t oOUT  = alloc((size_t)SB * D * 4);
  const size_t oOUT1 = alloc((size_t)SB * D * 4);
  const size_t oXBF  = alloc((size_t)SB * D * 2);
  const size_t oYBF  = alloc((size_t)SB * D * 2);
  const size_t oYBFA = alloc((size_t)SB * D * 2);
  const size_t oABUF = alloc((size_t)SB * D * 2);
  const size_t oKN   = alloc((size_t)FB * D * 2);
  const size_t oQU   = alloc((size_t)B * H * S * 64 * 2);
  const size_t oQV   = alloc((size_t)B * H * S * 64 * 2);
  const size_t oKBH  = alloc((size_t)B * H * F * 64 * 2);
  const size_t oVT   = alloc((size_t)B * H * F * 64 * 2);
  const size_t oRH   = alloc((size_t)H * F * 64 * 2);
  const size_t oUNI  = off;

  const size_t tmpBytes = (size_t)SB * D * 4 * 6;  // T1(3D)+T2(2D)+TG(1D)
  int Bc = 2;
  {
    size_t scB = (size_t)Bc * H * S * F * 4;
    size_t need = oUNI + (2 * scB > tmpBytes ? 2 * scB : tmpBytes);
    if (need > ws_size) Bc = 1;
  }
  const size_t scBytes = (size_t)Bc * H * S * F * 4;

  u16* WTp   = (u16*)(ws + oWT);
  u16* WETp  = (u16*)(ws + oWET);
  u16* PEBp  = (u16*)(ws + oPEB);
  float* OUTp  = (float*)(ws + oOUT);
  float* OUT1p = (float*)(ws + oOUT1);
  u16* XBFp  = (u16*)(ws + oXBF);
  u16* YBFp  = (u16*)(ws + oYBF);
  u16* YBFAp = (u16*)(ws + oYBFA);
  u16* ABUFp = (u16*)(ws + oABUF);
  u16* KNp   = (u16*)(ws + oKN);
  u16* QUp   = (u16*)(ws + oQU);
  u16* QVp   = (u16*)(ws + oQV);
  u16* KBHp  = (u16*)(ws + oKBH);
  u16* VTp   = (u16*)(ws + oVT);
  u16* RHp   = (u16*)(ws + oRH);
  float* Qf   = (float*)(ws + oUNI);
  float* SCp  = (float*)(ws + oUNI);
  float* POSp = (float*)(ws + oUNI + scBytes);
  float* T1   = (float*)(ws + oUNI);
  float* T2   = (float*)(ws + oUNI + (size_t)SB * 3 * D * 4);
  float* TGp  = (float*)(ws + oUNI + (size_t)SB * 5 * D * 4);
  u16* FFNBp  = (u16*)(ws + oUNI);

  auto gemm = [&](const u16* A, const u16* Bt, const float* bias, float* C32, u16* C16,
                  int M, int N, int K, int ldA, int ldB, int ldC,
                  long long sA, long long sBb, long long sBh, long long sC, int nH, int Z,
                  int flags) {
    dim3 grid((M + 127) / 128, (N + 127) / 128, Z);
    gemm_bt<<<grid, 256, 0, stream>>>(A, Bt, bias, C32, C16, M, N, K, ldA, ldB, ldC,
                                      sA, sBb, sBh, sC, nH, flags);
  };

  // positional encodings (bf16) + We^T
  pe_kernel<<<(F * D) / 256, 256, 0, stream>>>(PEBp);
  {
    WPack p{};
    p.nm = 1; p.src[0] = We; p.dst[0] = WETp; p.K[0] = IN; p.N[0] = D;
    p.tilePrefix[0] = 0; p.tilePrefix[1] = (IN / 32) * (D / 32);
    wtrans_kernel<<<p.tilePrefix[1], 256, 0, stream>>>(p);
  }
  // embed: x = gelu(h^T @ We + be)
  embed_conv<<<(SB * IN) / 256, 256, 0, stream>>>(h_in, ABUFp);
  gemm(ABUFp, WETp, be, OUTp, XBFp, SB, D, IN, IN, IN, D, 0, 0, 0, 0, 1, 1, 1 | 2 | 4 | 8);

  for (int li = 0; li < 4; ++li) {
    // ---- transpose this layer's weights to (N x K) bf16 ----
    WPack p{};
    int nt = 0, id = 0;
    auto addw = [&](const float* s, u16* d, int K, int N) {
      p.src[id] = s; p.dst[id] = d; p.K[id] = K; p.N[id] = N;
      p.tilePrefix[id] = nt; nt += (K / 32) * (N / 32); ++id;
    };
    addw(Wq + li * DD, WTp + 0 * DD, D, D);
    addw(Wk + li * DD, WTp + 1 * DD, D, D);
    addw(Wv + li * DD, WTp + 2 * DD, D, D);
    addw(Wr + li * DD, WTp + 3 * DD, D, D);
    addw(Wo + li * DD, WTp + 4 * DD, D, D);
    addw(gWr + (li * 2 + 0) * DD, WTp + 5 * DD, D, D);
    addw(gWz + (li * 2 + 0) * DD, WTp + 6 * DD, D, D);
    addw(gWg + (li * 2 + 0) * DD, WTp + 7 * DD, D, D);
    addw(gUr + (li * 2 + 0) * DD, WTp + 8 * DD, D, D);
    addw(gUz + (li * 2 + 0) * DD, WTp + 9 * DD, D, D);
    addw(gUg + (li * 2 + 0) * DD, WTp + 10 * DD, D, D);
    addw(gWr + (li * 2 + 1) * DD, WTp + 11 * DD, D, D);
    addw(gWz + (li * 2 + 1) * DD, WTp + 12 * DD, D, D);
    addw(gWg + (li * 2 + 1) * DD, WTp + 13 * DD, D, D);
    addw(gUr + (li * 2 + 1) * DD, WTp + 14 * DD, D, D);
    addw(gUz + (li * 2 + 1) * DD, WTp + 15 * DD, D, D);
    addw(gUg + (li * 2 + 1) * DD, WTp + 16 * DD, D, D);
    addw(fW1 + li * (long long)D * 4096, WTp + 17 * DD, D, 4096);
    addw(fW2 + li * (long long)4096 * D, WTp + 21 * DD, 4096, D);
    p.tilePrefix[id] = nt; p.nm = id;
    wtrans_kernel<<<nt, 256, 0, stream>>>(p);

    // ---- LN of [memory; out] -> KN (rows f*B+b); QN = rows [MB..) ----
    ln_kernel<<<FB, 256, 0, stream>>>(memory + (long long)li * MM * B * D, OUTp, MM * B,
                                      ln1s + li * D, ln1b + li * D, KNp);
    const u16* QN = KNp + (size_t)MM * B * D;

    // ---- projections ----
    gemm(QN, WTp + 0 * DD, bq + li * D, Qf, nullptr, SB, D, D, D, D, D, 0, 0, 0, 0, 1, 1, 2 | 4);
    prep_quv<<<(B * H * S * 64) / 256, 256, 0, stream>>>(Qf, uu + li * H * 64, vbp + li * H * 64, QUp, QVp);
    gemm(KNp, WTp + 1 * DD, bk + li * D, Qf, nullptr, FB, D, D, D, D, D, 0, 0, 0, 0, 1, 1, 2 | 4);
    prep_k<<<(B * H * F * 64) / 256, 256, 0, stream>>>(Qf, KBHp);
    gemm(KNp, WTp + 2 * DD, bv + li * D, Qf, nullptr, FB, D, D, D, D, D, 0, 0, 0, 0, 1, 1, 2 | 4);
    prep_vt<<<dim3(F / 64, B * H), 256, 0, stream>>>(Qf, VTp);
    gemm(PEBp, WTp + 3 * DD, br + li * D, Qf, nullptr, F, D, D, D, D, D, 0, 0, 0, 0, 1, 1, 2 | 4);
    prep_rh<<<(H * F * 64) / 256, 256, 0, stream>>>(Qf, RHp);

    // ---- attention, chunked over batch ----
    for (int bc0 = 0; bc0 < B; bc0 += Bc) {
      const int Z = Bc * H;
      gemm(QUp + (size_t)bc0 * H * S * 64, KBHp + (size_t)bc0 * H * F * 64, nullptr, SCp, nullptr,
           S, F, 64, 64, 64, F,
           (long long)S * 64, (long long)H * F * 64, (long long)F * 64, (long long)S * F, H, Z, 4);
      gemm(QVp + (size_t)bc0 * H * S * 64, RHp, nullptr, POSp, nullptr,
           S, F, 64, 64, 64, F,
           (long long)S * 64, 0, (long long)F * 64, (long long)S * F, H, Z, 4);
      softmax_kernel<<<dim3(S, Z), 256, 0, stream>>>(SCp, POSp);
      gemm((const u16*)SCp, VTp + (size_t)bc0 * H * 64 * F, nullptr, nullptr,
           YBFAp + (size_t)bc0 * D,
           S, 64, F, 2 * F, F, B * D,
           (long long)S * F * 2, (long long)H * 64 * F, (long long)64 * F, 64, H, Z, 8);
    }

    // ---- output projection: y = gelu(attn @ Wo + bo) (bf16) ----
    gemm(YBFAp, WTp + 4 * DD, bo + li * D, nullptr, YBFp, SB, D, D, D, D, D, 0, 0, 0, 0, 1, 1, 1 | 2 | 8);

    // ---- GRU1: out1 = gru(out, y) ----
    gemm(YBFp, WTp + 5 * DD, nullptr, T1, nullptr, SB, 3 * D, D, D, D, 3 * D, 0, 0, 0, 0, 1, 1, 4);
    gemm(XBFp, WTp + 8 * DD, nullptr, T2, nullptr, SB, 2 * D, D, D, D, 2 * D, 0, 0, 0, 0, 1, 1, 4);
    gru_elemA<<<(SB * D / 4) / 256, 256, 0, stream>>>(T1, T2, OUTp, ABUFp);
    gemm(ABUFp, WTp + 10 * DD, nullptr, TGp, nullptr, SB, D, D, D, D, D, 0, 0, 0, 0, 1, 1, 4);
    gru_elemB<<<(SB * D / 4) / 256, 256, 0, stream>>>(T1, T2, TGp, OUTp, OUT1p, XBFp);

    // ---- FFN ----
    ln_kernel<<<SB, 256, 0, stream>>>(OUT1p, OUT1p, SB, ln2s + li * D, ln2b + li * D, ABUFp);
    gemm(ABUFp, WTp + 17 * DD, fb1 + li * 4096, nullptr, FFNBp, SB, 4096, D, D, D, 4096,
         0, 0, 0, 0, 1, 1, 1 | 2 | 8);
    gemm(FFNBp, WTp + 21 * DD, fb2 + li * D, nullptr, YBFp, SB, D, 4096, 4096, 4096, D,
         0, 0, 0, 0, 1, 1, 1 | 2 | 8);

    // ---- GRU2: out = gru(out1, e3) ----
    gemm(YBFp, WTp + 11 * DD, nullptr, T1, nullptr, SB, 3 * D, D, D, D, 3 * D, 0, 0, 0, 0, 1, 1, 4);
    gemm(XBFp, WTp + 14 * DD, nullptr, T2, nullptr, SB, 2 * D, D, D, D, 2 * D, 0, 0, 0, 0, 1, 1, 4);
    gru_elemA<<<(SB * D / 4) / 256, 256, 0, stream>>>(T1, T2, OUT1p, ABUFp);
    gemm(ABUFp, WTp + 16 * DD, nullptr, TGp, nullptr, SB, D, D, D, D, D, 0, 0, 0, 0, 1, 1, 4);
    gru_elemB<<<(SB * D / 4) / 256, 256, 0, stream>>>(T1, T2, TGp, OUT1p, OUTp, XBFp);
  }

  out_transpose<<<(SB * D / 4) / 256, 256, 0, stream>>>(OUTp, (float*)d_out);
}

// Round 3
// 3539.449 us; speedup vs baseline: 1.5429x; 1.3764x over previous
//
#include <hip/hip_runtime.h>

typedef unsigned short u16;
typedef unsigned long long u64;
typedef __attribute__((ext_vector_type(8))) short bf16x8;
typedef __attribute__((ext_vector_type(4))) float f32x4;

#define DEVI __device__ __forceinline__

DEVI u16 f2b(float f) {
  unsigned u = __float_as_uint(f);
  u += 0x7fffu + ((u >> 16) & 1u);
  return (u16)(u >> 16);
}
DEVI float b2f(u16 v) { return __uint_as_float((unsigned)v << 16); }
DEVI float gelu_f(float x) { return 0.5f * x * (1.f + erff(x * 0.70710678118654752f)); }
DEVI float sigm_f(float x) { return 1.f / (1.f + expf(-x)); }

DEVI void gload16(const void* g, void* l) {
  __builtin_amdgcn_global_load_lds((__attribute__((address_space(1))) void*)g,
                                   (__attribute__((address_space(3))) void*)l, 16, 0, 0);
}

// ---------------------------------------------------------------------------
// Generic batched GEMM:  C[z] = act(A[z] (MxK) @ Bt[z]^T + bias), Bt is (N x K).
// flags: 1=gelu, 2=bias, 4=store f32, 8=store bf16
// T3-minimum 2-phase pipeline (double-buffered LDS, stage(t+1) before compute(t)).
// ---------------------------------------------------------------------------
__global__ __launch_bounds__(256) void gemm_bt(
    const u16* __restrict__ A, const u16* __restrict__ Bt,
    const float* __restrict__ bias, float* __restrict__ C32, u16* __restrict__ C16,
    int M, int N, int K, int ldA, int ldB, int ldC,
    long long sA, long long sBb, long long sBh, long long sC, int nH, int flags)
{
  __shared__ __align__(16) u16 Sm[2][256 * 64];
  const int z = blockIdx.z;
  const int zb = z / nH, zh = z - zb * nH;
  A  += (long long)z * sA;
  Bt += (long long)zb * sBb + (long long)zh * sBh;
  const long long cOff = (long long)z * sC;
  const int m0 = blockIdx.x * 128, n0 = blockIdx.y * 128;
  const int t = threadIdx.x, lane = t & 63;
  const int wm = ((t >> 7) & 1) * 64, wn = ((t >> 6) & 1) * 64;

  f32x4 acc[4][4];
#pragma unroll
  for (int i = 0; i < 4; ++i)
#pragma unroll
    for (int j = 0; j < 4; ++j) { f32x4 zz = {0.f, 0.f, 0.f, 0.f}; acc[i][j] = zz; }

  auto stage = [&](int buf, int k0) {
#pragma unroll
    for (int r = 0; r < 4; ++r) {
      const int c = r * 256 + t;
      const int row = c >> 3;
      const int col = (c & 7) << 3;
      int ga = m0 + row; if (ga >= M) ga = M - 1;
      gload16(A + (long long)ga * ldA + (k0 + col),
              &Sm[buf][(size_t)(r * 256 + (t & 192)) * 8]);
      int gb = n0 + row; if (gb >= N) gb = N - 1;
      gload16(Bt + (long long)gb * ldB + (k0 + col),
              &Sm[buf][(size_t)(1024 + r * 256 + (t & 192)) * 8]);
    }
  };

  auto compute = [&](int buf) {
    const u16* As = &Sm[buf][0];
    const u16* Bs = &Sm[buf][128 * 64];
#pragma unroll
    for (int ks = 0; ks < 2; ++ks) {
      const int ko = ks * 32 + ((lane >> 4) << 3);
      bf16x8 af[4], bfv[4];
#pragma unroll
      for (int i = 0; i < 4; ++i)
        af[i] = *(const bf16x8*)&As[(wm + i * 16 + (lane & 15)) * 64 + ko];
#pragma unroll
      for (int i = 0; i < 4; ++i)
        bfv[i] = *(const bf16x8*)&Bs[(wn + i * 16 + (lane & 15)) * 64 + ko];
#pragma unroll
      for (int mi = 0; mi < 4; ++mi)
#pragma unroll
        for (int ni = 0; ni < 4; ++ni)
          acc[mi][ni] = __builtin_amdgcn_mfma_f32_16x16x32_bf16(af[mi], bfv[ni], acc[mi][ni], 0, 0, 0);
    }
  };

  stage(0, 0);
  __syncthreads();
  int cur = 0;
  for (int k0 = 64; k0 < K; k0 += 64) {
    stage(cur ^ 1, k0);
    compute(cur);
    __syncthreads();
    cur ^= 1;
  }
  compute(cur);

  const int cb = n0 + wn + (lane & 15);
  const int rb = m0 + wm + ((lane >> 4) << 2);
#pragma unroll
  for (int ni = 0; ni < 4; ++ni) {
    const int col = cb + ni * 16;
    if (col >= N) continue;
    const float bv = (flags & 2) ? bias[col] : 0.f;
#pragma unroll
    for (int mi = 0; mi < 4; ++mi) {
#pragma unroll
      for (int q = 0; q < 4; ++q) {
        const int row = rb + mi * 16 + q;
        if (row >= M) continue;
        float x = acc[mi][ni][q] + bv;
        if (flags & 1) x = gelu_f(x);
        const long long o = cOff + (long long)row * ldC + col;
        if (flags & 4) C32[o] = x;
        if (flags & 8) C16[o] = f2b(x);
      }
    }
  }
}

// ---------------------------------------------------------------------------
// Fused rel-pos attention (flash-style). Block = 64 q-rows of one (b,h).
// scores(i,j) = (q_i·k_j + u·k_j + q_i·r_{j-i+511} + vb·r_{j-i+511})/8, masked
// j-i>512; online softmax; O = P V. Never materializes S x F in HBM.
// Tile band: c0 = j0-i0+448 is 64-aligned; band width 127 -> 2 R tiles,
// sliding window (one new R tile per kv step).
// All 64x64 bf16 LDS tiles use granule-XOR swizzle (g ^= row&7) applied on
// BOTH the global source and the LDS read (global_load_lds is linear-dest).
// ---------------------------------------------------------------------------
__global__ __launch_bounds__(256) void fused_attn(
    const u16* __restrict__ Qb,   // [bh][s][64]
    const u16* __restrict__ Kb,   // [bh][f][64]
    const u16* __restrict__ Vt,   // [bh][d][1024]
    const u16* __restrict__ Rh,   // [h][c][64]
    const float* __restrict__ uK,  // [bh][f]
    const float* __restrict__ vbR, // [h][c]
    u16* __restrict__ Y)           // [s][b*1024 + h*64 + d]
{
  constexpr int F = 1024;
  const int i0 = blockIdx.x * 64;
  const int bh = blockIdx.y;
  const int h = bh & 15;

  __shared__ __align__(16) u16 Qs[64 * 64];
  __shared__ __align__(16) u16 Ks[64 * 64];
  __shared__ __align__(16) u16 Vs[64 * 64];
  __shared__ __align__(16) u16 Rs[2][64 * 64];
  __shared__ u16 PBs[64][132];            // pos logits band, bf16, padded
  __shared__ __align__(16) u16 Ps[4][16][72];  // per-wave P tiles, padded
  __shared__ float uKs[64];
  __shared__ float vbRs[2][64];

  const int t = threadIdx.x;
  const int lane = t & 63;
  const int wq = t >> 6;           // wave id -> q-row block [16*wq, 16*wq+16)
  const int l15 = lane & 15, lhi = lane >> 4;

  const u16* Qg = Qb + ((size_t)bh * 512 + i0) * 64;
  const u16* Kg = Kb + (size_t)bh * F * 64;
  const u16* Vg = Vt + (size_t)bh * 64 * F;
  const u16* Rg = Rh + (size_t)h * F * 64;
  const float* uKg = uK + (size_t)bh * F;
  const float* vbRg = vbR + (size_t)h * F;

  auto stageQ = [&]() {
#pragma unroll
    for (int rnd = 0; rnd < 2; ++rnd) {
      const int idx = rnd * 256 + t;
      const int row = idx >> 3;
      const int gs = (idx & 7) ^ (row & 7);
      gload16(Qg + row * 64 + gs * 8, Qs + (size_t)(rnd * 256 + (t & 192)) * 8);
    }
  };
  auto stageK = [&](int j0) {
#pragma unroll
    for (int rnd = 0; rnd < 2; ++rnd) {
      const int idx = rnd * 256 + t;
      const int row = idx >> 3;
      const int gs = (idx & 7) ^ (row & 7);
      gload16(Kg + (j0 + row) * 64 + gs * 8, Ks + (size_t)(rnd * 256 + (t & 192)) * 8);
    }
  };
  auto stageV = [&](int j0) {
#pragma unroll
    for (int rnd = 0; rnd < 2; ++rnd) {
      const int idx = rnd * 256 + t;
      const int row = idx >> 3;
      const int gs = (idx & 7) ^ (row & 7);
      gload16(Vg + row * F + j0 + gs * 8, Vs + (size_t)(rnd * 256 + (t & 192)) * 8);
    }
  };
  auto stageR = [&](u16* dst, int cbase) {
#pragma unroll
    for (int rnd = 0; rnd < 2; ++rnd) {
      const int idx = rnd * 256 + t;
      const int row = idx >> 3;
      const int gs = (idx & 7) ^ (row & 7);
      int grow = cbase + row; if (grow > 1023) grow = 1023;
      gload16(Rg + grow * 64 + gs * 8, dst + (size_t)(rnd * 256 + (t & 192)) * 8);
    }
  };

  // prologue: Q tile + first R lo tile + vbR lo
  stageQ();
  const int c_lo0 = 448 - i0;  // >= 0 (i0 <= 448)
  stageR(Rs[0], c_lo0);
  if (t < 64) {
    int c = c_lo0 + t; if (c > 1023) c = 1023;
    vbRs[0][t] = vbRg[c];
  }

  f32x4 Oacc[4];
#pragma unroll
  for (int i = 0; i < 4; ++i) { f32x4 zz = {0.f, 0.f, 0.f, 0.f}; Oacc[i] = zz; }
  float mrow[4] = {-3.0e38f, -3.0e38f, -3.0e38f, -3.0e38f};
  float lrow[4] = {0.f, 0.f, 0.f, 0.f};

  const int nT = i0 / 64 + 9;
  for (int st = 0; st < nT; ++st) {
    const int j0 = st * 64;
    const int c_hi = j0 - i0 + 512;
    __syncthreads();   // A: previous compute done, safe to overwrite tiles
    stageK(j0);
    stageV(j0);
    stageR(Rs[(st + 1) & 1], c_hi);
    if (t < 64) uKs[t] = uKg[j0 + t];
    else if (t < 128) {
      int c = c_hi + (t - 64); if (c > 1023) c = 1023;
      vbRs[(st + 1) & 1][t - 64] = vbRg[c];
    }
    __syncthreads();   // B: staged data visible (vmcnt drain)

    const u16* RsLo = Rs[st & 1];
    const u16* RsHi = Rs[(st + 1) & 1];
    const float* vLo = vbRs[st & 1];
    const float* vHi = vbRs[(st + 1) & 1];

    // ---- content + position-band MFMAs (shared A = q) ----
    f32x4 cacc[4], pbacc[8];
#pragma unroll
    for (int i = 0; i < 4; ++i) { f32x4 zz = {0.f, 0.f, 0.f, 0.f}; cacc[i] = zz; }
#pragma unroll
    for (int i = 0; i < 8; ++i) { f32x4 zz = {0.f, 0.f, 0.f, 0.f}; pbacc[i] = zz; }
#pragma unroll
    for (int ks = 0; ks < 2; ++ks) {
      const int arow = wq * 16 + l15;
      const bf16x8 a = *(const bf16x8*)&Qs[arow * 64 + (((ks * 4 + lhi) ^ (arow & 7)) << 3)];
#pragma unroll
      for (int ni = 0; ni < 4; ++ni) {
        const int brow = ni * 16 + l15;
        const bf16x8 bk_ = *(const bf16x8*)&Ks[brow * 64 + (((ks * 4 + lhi) ^ (brow & 7)) << 3)];
        cacc[ni] = __builtin_amdgcn_mfma_f32_16x16x32_bf16(a, bk_, cacc[ni], 0, 0, 0);
      }
#pragma unroll
      for (int ni = 0; ni < 8; ++ni) {
        const int brow = (ni & 3) * 16 + l15;
        const u16* rt = (ni < 4) ? RsLo : RsHi;
        const bf16x8 br_ = *(const bf16x8*)&rt[brow * 64 + (((ks * 4 + lhi) ^ (brow & 7)) << 3)];
        pbacc[ni] = __builtin_amdgcn_mfma_f32_16x16x32_bf16(a, br_, pbacc[ni], 0, 0, 0);
      }
    }
    // write PB band to LDS (intra-wave rows only)
#pragma unroll
    for (int ni = 0; ni < 8; ++ni)
#pragma unroll
      for (int qq = 0; qq < 4; ++qq)
        PBs[wq * 16 + lhi * 4 + qq][ni * 16 + l15] = f2b(pbacc[ni][qq]);

    // ---- build scores ----
    const int lim = i0 - j0 + 512;
    float sc[4][4];
#pragma unroll
    for (int ni = 0; ni < 4; ++ni) {
      const int dj = ni * 16 + l15;
      const float uk = uKs[dj];
#pragma unroll
      for (int qq = 0; qq < 4; ++qq) {
        const int di = wq * 16 + lhi * 4 + qq;
        const int cc = dj - di + 63;                // [0,126]
        const float pb = b2f(PBs[di][cc]);
        const float vr = (cc < 64) ? vLo[cc] : vHi[cc - 64];
        float s = (cacc[ni][qq] + uk + pb + vr) * 0.125f;
        if (dj - di > lim) s = -1e30f;
        sc[ni][qq] = s;
      }
    }

    // ---- online softmax (per wave; rows wave-exclusive) ----
    float nm[4], esc[4];
#pragma unroll
    for (int qq = 0; qq < 4; ++qq) {
      float r = fmaxf(fmaxf(sc[0][qq], sc[1][qq]), fmaxf(sc[2][qq], sc[3][qq]));
      r = fmaxf(r, __shfl_xor(r, 1));
      r = fmaxf(r, __shfl_xor(r, 2));
      r = fmaxf(r, __shfl_xor(r, 4));
      r = fmaxf(r, __shfl_xor(r, 8));
      nm[qq] = fmaxf(mrow[qq], r);
      esc[qq] = expf(mrow[qq] - nm[qq]);
      mrow[qq] = nm[qq];
    }
    float ps[4][4];
    float rsum[4] = {0.f, 0.f, 0.f, 0.f};
#pragma unroll
    for (int ni = 0; ni < 4; ++ni)
#pragma unroll
      for (int qq = 0; qq < 4; ++qq) {
        float p = expf(sc[ni][qq] - nm[qq]);
        ps[ni][qq] = p;
        rsum[qq] += p;
      }
#pragma unroll
    for (int qq = 0; qq < 4; ++qq) {
      float r = rsum[qq];
      r += __shfl_xor(r, 1);
      r += __shfl_xor(r, 2);
      r += __shfl_xor(r, 4);
      r += __shfl_xor(r, 8);
      lrow[qq] = lrow[qq] * esc[qq] + r;
    }
    // rescale O
#pragma unroll
    for (int nd = 0; nd < 4; ++nd)
#pragma unroll
      for (int qq = 0; qq < 4; ++qq) Oacc[nd][qq] *= esc[qq];

    // ---- P -> LDS (bf16) -> PV MFMA ----
#pragma unroll
    for (int ni = 0; ni < 4; ++ni)
#pragma unroll
      for (int qq = 0; qq < 4; ++qq)
        Ps[wq][lhi * 4 + qq][ni * 16 + l15] = f2b(ps[ni][qq]);
#pragma unroll
    for (int ks = 0; ks < 2; ++ks) {
      const bf16x8 pa = *(const bf16x8*)&Ps[wq][l15][ks * 32 + lhi * 8];
#pragma unroll
      for (int nd = 0; nd < 4; ++nd) {
        const int vrow = nd * 16 + l15;
        const bf16x8 vb_ = *(const bf16x8*)&Vs[vrow * 64 + (((ks * 4 + lhi) ^ (vrow & 7)) << 3)];
        Oacc[nd] = __builtin_amdgcn_mfma_f32_16x16x32_bf16(pa, vb_, Oacc[nd], 0, 0, 0);
      }
    }
  }

  // epilogue: normalize and store
  float inv[4];
#pragma unroll
  for (int qq = 0; qq < 4; ++qq) inv[qq] = 1.f / lrow[qq];
  const int b = bh >> 4;
#pragma unroll
  for (int nd = 0; nd < 4; ++nd)
#pragma unroll
    for (int qq = 0; qq < 4; ++qq) {
      const int row = i0 + wq * 16 + lhi * 4 + qq;
      const int d = nd * 16 + l15;
      Y[(size_t)row * 8192 + b * 1024 + h * 64 + d] = f2b(Oacc[nd][qq] * inv[qq]);
    }
}

// ---------------------------------------------------------------------------
// rank-1 terms: uK[bh][f] = u[h]·K[bh][f][:],  vbR[h][c] = vb[h]·R[h][c][:]
// ---------------------------------------------------------------------------
__global__ __launch_bounds__(256) void uk_kernel(const u16* __restrict__ Kb,
                                                 const float* __restrict__ u,
                                                 float* __restrict__ uK)
{
  const long long idx = (long long)blockIdx.x * 256 + threadIdx.x;  // bh*F + f
  const int h = (int)((idx >> 10) & 15);
  const u16* k = Kb + idx * 64;
  const float* uh = u + h * 64;
  float s = 0.f;
#pragma unroll
  for (int j = 0; j < 8; ++j) {
    bf16x8 kv = *(const bf16x8*)&k[j * 8];
#pragma unroll
    for (int e = 0; e < 8; ++e) s += b2f((u16)kv[e]) * uh[j * 8 + e];
  }
  uK[idx] = s;
}

__global__ __launch_bounds__(256) void vbr_kernel(const u16* __restrict__ Rh,
                                                  const float* __restrict__ vb,
                                                  float* __restrict__ vbR)
{
  const long long idx = (long long)blockIdx.x * 256 + threadIdx.x;  // h*F + c
  const int h = (int)(idx >> 10);
  const u16* r = Rh + idx * 64;
  const float* vh = vb + h * 64;
  float s = 0.f;
#pragma unroll
  for (int j = 0; j < 8; ++j) {
    bf16x8 rv = *(const bf16x8*)&r[j * 8];
#pragma unroll
    for (int e = 0; e < 8; ++e) s += b2f((u16)rv[e]) * vh[j * 8 + e];
  }
  vbR[idx] = s;
}

// ---------------------------------------------------------------------------
// Weight transpose+convert: src (K x N) f32  ->  dst (N x K) bf16. Dims %32==0.
// ---------------------------------------------------------------------------
#define MAXW 20
struct WPack {
  const float* src[MAXW];
  u16* dst[MAXW];
  int K[MAXW], N[MAXW];
  int tilePrefix[MAXW + 1];
  int nm;
};

__global__ __launch_bounds__(256) void wtrans_kernel(WPack p) {
  int bid = blockIdx.x;
  int m = 0;
  while (m < p.nm && bid >= p.tilePrefix[m + 1]) ++m;
  if (m >= p.nm) return;
  const int lt = bid - p.tilePrefix[m];
  const int K = p.K[m], N = p.N[m];
  const int tN = N >> 5;
  const int kt = lt / tN, nt = lt - kt * tN;
  const int k0 = kt << 5, n0 = nt << 5;
  const float* src = p.src[m];
  u16* dst = p.dst[m];
  __shared__ float tile[32][33];
  const int t = threadIdx.x;
  const int r = t >> 3, c4 = (t & 7) << 2;
  float4 v = *(const float4*)&src[(size_t)(k0 + r) * N + n0 + c4];
  tile[r][c4 + 0] = v.x; tile[r][c4 + 1] = v.y; tile[r][c4 + 2] = v.z; tile[r][c4 + 3] = v.w;
  __syncthreads();
  u16 o0 = f2b(tile[c4 + 0][r]);
  u16 o1 = f2b(tile[c4 + 1][r]);
  u16 o2 = f2b(tile[c4 + 2][r]);
  u16 o3 = f2b(tile[c4 + 3][r]);
  u64 w = (u64)o0 | ((u64)o1 << 16) | ((u64)o2 << 32) | ((u64)o3 << 48);
  *(u64*)&dst[(size_t)(n0 + r) * K + k0 + c4] = w;
}

// ---------------------------------------------------------------------------
// LayerNorm over D=1024; rows [0,rowsMem) from Xmem, rest from Xout. bf16 out.
// ---------------------------------------------------------------------------
__global__ __launch_bounds__(256) void ln_kernel(
    const float* __restrict__ Xmem, const float* __restrict__ Xout, int rowsMem,
    const float* __restrict__ sc, const float* __restrict__ bi, u16* __restrict__ dst)
{
  const int row = blockIdx.x;
  const float* src = (row < rowsMem) ? (Xmem + (long long)row * 1024)
                                     : (Xout + (long long)(row - rowsMem) * 1024);
  const int t = threadIdx.x;
  float4 v = *(const float4*)&src[t * 4];
  float s1 = v.x + v.y + v.z + v.w;
  float s2 = v.x * v.x + v.y * v.y + v.z * v.z + v.w * v.w;
#pragma unroll
  for (int o = 32; o > 0; o >>= 1) { s1 += __shfl_down(s1, o); s2 += __shfl_down(s2, o); }
  __shared__ float red[8];
  const int wv = t >> 6;
  if ((t & 63) == 0) { red[wv * 2] = s1; red[wv * 2 + 1] = s2; }
  __syncthreads();
  s1 = red[0] + red[2] + red[4] + red[6];
  s2 = red[1] + red[3] + red[5] + red[7];
  const float mu = s1 * (1.f / 1024.f);
  const float var = s2 * (1.f / 1024.f) - mu * mu;
  const float rs = rsqrtf(var + 1e-5f);
  float vals[4] = {v.x, v.y, v.z, v.w};
  u16 o4[4];
#pragma unroll
  for (int j = 0; j < 4; ++j) {
    const int c = t * 4 + j;
    o4[j] = f2b((vals[j] - mu) * rs * sc[c] + bi[c]);
  }
  *(u64*)&dst[(long long)row * 1024 + t * 4] =
      (u64)o4[0] | ((u64)o4[1] << 16) | ((u64)o4[2] << 32) | ((u64)o4[3] << 48);
}

// ---------------------------------------------------------------------------
// small prep / elementwise kernels
// ---------------------------------------------------------------------------
__global__ __launch_bounds__(256) void prep_q(const float* __restrict__ Qf, u16* __restrict__ QB)
{
  const long long idx = (long long)blockIdx.x * 256 + threadIdx.x;  // B*H*S*64
  const int d2 = idx & 63;
  const int s = (idx >> 6) & 511;
  const int h = (idx >> 15) & 15;
  const int b = (int)(idx >> 19);
  QB[idx] = f2b(Qf[(((long long)s * 8 + b) << 10) + h * 64 + d2]);
}

__global__ __launch_bounds__(256) void prep_k(const float* __restrict__ Kf, u16* __restrict__ KBH)
{
  const long long idx = (long long)blockIdx.x * 256 + threadIdx.x;  // B*H*F*64
  const int d2 = idx & 63;
  const int f = (idx >> 6) & 1023;
  const int h = (idx >> 16) & 15;
  const int b = (int)(idx >> 20);
  KBH[idx] = f2b(Kf[(((long long)f * 8 + b) << 10) + h * 64 + d2]);
}

__global__ __launch_bounds__(256) void prep_vt(const float* __restrict__ Vf, u16* __restrict__ VT)
{
  const int f0 = blockIdx.x * 64;
  const int bh = blockIdx.y;
  const int b = bh >> 4, h = bh & 15;
  __shared__ u16 tl[64 * 64];
  const int t = threadIdx.x;
  {
    const int fr = t >> 2, c0 = (t & 3) * 16;
#pragma unroll
    for (int j = 0; j < 16; j += 4) {
      float4 v = *(const float4*)&Vf[(((long long)(f0 + fr) * 8 + b) << 10) + h * 64 + c0 + j];
      tl[fr * 64 + c0 + j + 0] = f2b(v.x);
      tl[fr * 64 + c0 + j + 1] = f2b(v.y);
      tl[fr * 64 + c0 + j + 2] = f2b(v.z);
      tl[fr * 64 + c0 + j + 3] = f2b(v.w);
    }
  }
  __syncthreads();
  {
    const int dr = t >> 2, c0 = (t & 3) * 16;
    u16* dst = VT + ((long long)bh * 64 + dr) * 1024 + f0 + c0;
#pragma unroll
    for (int j = 0; j < 16; ++j) dst[j] = tl[(c0 + j) * 64 + dr];
  }
}

__global__ __launch_bounds__(256) void prep_rh(const float* __restrict__ Rf, u16* __restrict__ RH)
{
  const long long idx = (long long)blockIdx.x * 256 + threadIdx.x;  // H*F*64
  const int d2 = idx & 63;
  const int tt = (idx >> 6) & 1023;
  const int h = (int)(idx >> 16);
  RH[idx] = f2b(Rf[((long long)tt << 10) + h * 64 + d2]);
}

__global__ __launch_bounds__(256) void pe_kernel(u16* __restrict__ PEB)
{
  const long long idx = (long long)blockIdx.x * 256 + threadIdx.x;  // F*D
  const int p = (int)(idx >> 10);
  const int d = idx & 1023;
  const int q = d & 511;
  const float inv = powf(10000.f, -(float)(2 * q) * (1.f / 1024.f));
  const float ang = (float)(1023 - p) * inv;
  PEB[idx] = f2b((d < 512) ? sinf(ang) : cosf(ang));
}

__global__ __launch_bounds__(256) void embed_conv(const float* __restrict__ h, u16* __restrict__ A)
{
  const long long idx = (long long)blockIdx.x * 256 + threadIdx.x;  // SB*IN
  const int c = idx & 127;
  const int r = (int)(idx >> 7);
  const int s = r >> 3, b = r & 7;
  A[idx] = f2b(h[(((long long)b * 512 + s) << 7) + c]);
}

__global__ __launch_bounds__(256) void gru_elemA(const float* __restrict__ T1, float* __restrict__ T2,
                                                 const float* __restrict__ X, u16* __restrict__ RXBF)
{
  const long long i4 = ((long long)blockIdx.x * 256 + threadIdx.x) * 4;  // SB*D
  const int row = (int)(i4 >> 10);
  const int c = i4 & 1023;
  const float* t1 = T1 + (long long)row * 3072 + c;
  float* t2 = T2 + (long long)row * 2048 + c;
  float4 ry = *(const float4*)t1;
  float4 zy = *(const float4*)(t1 + 1024);
  float4 rx = *(const float4*)t2;
  float4 zx = *(const float4*)(t2 + 1024);
  float4 x = *(const float4*)(X + i4);
  float rr[4], zz[4];
  rr[0] = sigm_f(ry.x + rx.x); rr[1] = sigm_f(ry.y + rx.y);
  rr[2] = sigm_f(ry.z + rx.z); rr[3] = sigm_f(ry.w + rx.w);
  zz[0] = sigm_f(zy.x + zx.x - 2.f); zz[1] = sigm_f(zy.y + zx.y - 2.f);
  zz[2] = sigm_f(zy.z + zx.z - 2.f); zz[3] = sigm_f(zy.w + zx.w - 2.f);
  u16 o4[4];
  o4[0] = f2b(rr[0] * x.x); o4[1] = f2b(rr[1] * x.y);
  o4[2] = f2b(rr[2] * x.z); o4[3] = f2b(rr[3] * x.w);
  *(u64*)&RXBF[i4] = (u64)o4[0] | ((u64)o4[1] << 16) | ((u64)o4[2] << 32) | ((u64)o4[3] << 48);
  float4 zo; zo.x = zz[0]; zo.y = zz[1]; zo.z = zz[2]; zo.w = zz[3];
  *(float4*)t2 = zo;
}

__global__ __launch_bounds__(256) void gru_elemB(const float* __restrict__ T1, const float* __restrict__ T2,
                                                 const float* __restrict__ TG, const float* __restrict__ X,
                                                 float* __restrict__ O, u16* __restrict__ XBF)
{
  const long long i4 = ((long long)blockIdx.x * 256 + threadIdx.x) * 4;
  const int row = (int)(i4 >> 10);
  const int c = i4 & 1023;
  float4 gy = *(const float4*)(T1 + (long long)row * 3072 + 2048 + c);
  float4 tt = *(const float4*)(TG + i4);
  float4 z = *(const float4*)(T2 + (long long)row * 2048 + c);
  float4 x = *(const float4*)(X + i4);
  float4 o;
  o.x = (1.f - z.x) * x.x + z.x * tanhf(gy.x + tt.x);
  o.y = (1.f - z.y) * x.y + z.y * tanhf(gy.y + tt.y);
  o.z = (1.f - z.z) * x.z + z.z * tanhf(gy.z + tt.z);
  o.w = (1.f - z.w) * x.w + z.w * tanhf(gy.w + tt.w);
  *(float4*)(O + i4) = o;
  u16 o4[4];
  o4[0] = f2b(o.x); o4[1] = f2b(o.y); o4[2] = f2b(o.z); o4[3] = f2b(o.w);
  *(u64*)&XBF[i4] = (u64)o4[0] | ((u64)o4[1] << 16) | ((u64)o4[2] << 32) | ((u64)o4[3] << 48);
}

__global__ __launch_bounds__(256) void out_transpose(const float* __restrict__ O, float* __restrict__ dst)
{
  const long long i4 = ((long long)blockIdx.x * 256 + threadIdx.x) * 4;
  const int d = i4 & 1023;
  const int r = (int)(i4 >> 10);
  const int s = r >> 3, b = r & 7;
  float4 v = *(const float4*)(O + i4);
  *(float4*)&dst[(((long long)b * 512 + s) << 10) + d] = v;
}

// ---------------------------------------------------------------------------
extern "C" void kernel_launch(void* const* d_in, const int* in_sizes, int n_in,
                              void* d_out, int out_size, void* d_ws, size_t ws_size,
                              hipStream_t stream)
{
  (void)in_sizes; (void)n_in; (void)out_size; (void)ws_size;
  const float* h_in   = (const float*)d_in[0];
  const float* memory = (const float*)d_in[1];
  const float* We     = (const float*)d_in[2];
  const float* be     = (const float*)d_in[3];
  const float* ln1s   = (const float*)d_in[4];
  const float* ln1b   = (const float*)d_in[5];
  const float* ln2s   = (const float*)d_in[6];
  const float* ln2b   = (const float*)d_in[7];
  const float* Wq     = (const float*)d_in[8];
  const float* bq     = (const float*)d_in[9];
  const float* Wk     = (const float*)d_in[10];
  const float* bk     = (const float*)d_in[11];
  const float* Wv     = (const float*)d_in[12];
  const float* bv     = (const float*)d_in[13];
  const float* Wr     = (const float*)d_in[14];
  const float* br     = (const float*)d_in[15];
  const float* Wo     = (const float*)d_in[16];
  const float* bo     = (const float*)d_in[17];
  const float* uu     = (const float*)d_in[18];
  const float* vbp    = (const float*)d_in[19];
  const float* gWr    = (const float*)d_in[20];
  const float* gUr    = (const float*)d_in[21];
  const float* gWz    = (const float*)d_in[22];
  const float* gUz    = (const float*)d_in[23];
  const float* gWg    = (const float*)d_in[24];
  const float* gUg    = (const float*)d_in[25];
  const float* fW1    = (const float*)d_in[26];
  const float* fb1    = (const float*)d_in[27];
  const float* fW2    = (const float*)d_in[28];
  const float* fb2    = (const float*)d_in[29];

  constexpr int S = 512, MM = 512, B = 8, D = 1024, H = 16, IN = 128, F = 1024;
  constexpr int SB = 4096, FB = 8192;
  constexpr long long DD = (long long)D * D;

  char* ws = (char*)d_ws;
  size_t off = 0;
  auto alloc = [&](size_t bytes) -> size_t {
    size_t o = off; off = (off + bytes + 255) & ~(size_t)255; return o;
  };
  const size_t oWT   = alloc((size_t)25 * DD * 2);
  const size_t oWET  = alloc((size_t)D * IN * 2);
  const size_t oPEB  = alloc((size_t)F * D * 2);
  const size_t oOUT  = alloc((size_t)SB * D * 4);
  const size_t oOUT1 = alloc((size_t)SB * D * 4);
  const size_t oXBF  = alloc((size_t)SB * D * 2);
  const size_t oYBF  = alloc((size_t)SB * D * 2);
  const size_t oYBFA = alloc((size_t)SB * D * 2);
  const size_t oABUF = alloc((size_t)SB * D * 2);
  const size_t oKN   = alloc((size_t)FB * D * 2);
  const size_t oQB   = alloc((size_t)B * H * S * 64 * 2);
  const size_t oKBH  = alloc((size_t)B * H * F * 64 * 2);
  const size_t oVT   = alloc((size_t)B * H * F * 64 * 2);
  const size_t oRH   = alloc((size_t)H * F * 64 * 2);
  const size_t oUK   = alloc((size_t)B * H * F * 4);
  const size_t oVBR  = alloc((size_t)H * F * 4);
  const size_t oUNI  = off;

  u16* WTp   = (u16*)(ws + oWT);
  u16* WETp  = (u16*)(ws + oWET);
  u16* PEBp  = (u16*)(ws + oPEB);
  float* OUTp  = (float*)(ws + oOUT);
  float* OUT1p = (float*)(ws + oOUT1);
  u16* XBFp  = (u16*)(ws + oXBF);
  u16* YBFp  = (u16*)(ws + oYBF);
  u16* YBFAp = (u16*)(ws + oYBFA);
  u16* ABUFp = (u16*)(ws + oABUF);
  u16* KNp   = (u16*)(ws + oKN);
  u16* QBp   = (u16*)(ws + oQB);
  u16* KBHp  = (u16*)(ws + oKBH);
  u16* VTp   = (u16*)(ws + oVT);
  u16* RHp   = (u16*)(ws + oRH);
  float* uKp  = (float*)(ws + oUK);
  float* vbRp = (float*)(ws + oVBR);
  float* Qf   = (float*)(ws + oUNI);
  float* T1   = (float*)(ws + oUNI);
  float* T2   = (float*)(ws + oUNI + (size_t)SB * 3 * D * 4);
  float* TGp  = (float*)(ws + oUNI + (size_t)SB * 5 * D * 4);
  u16* FFNBp  = (u16*)(ws + oUNI);

  auto gemm = [&](const u16* A, const u16* Bt, const float* bias, float* C32, u16* C16,
                  int M, int N, int K, int ldA, int ldB, int ldC,
                  long long sA, long long sBb, long long sBh, long long sC, int nH, int Z,
                  int flags) {
    dim3 grid((M + 127) / 128, (N + 127) / 128, Z);
    gemm_bt<<<grid, 256, 0, stream>>>(A, Bt, bias, C32, C16, M, N, K, ldA, ldB, ldC,
                                      sA, sBb, sBh, sC, nH, flags);
  };

  pe_kernel<<<(F * D) / 256, 256, 0, stream>>>(PEBp);
  {
    WPack p{};
    p.nm = 1; p.src[0] = We; p.dst[0] = WETp; p.K[0] = IN; p.N[0] = D;
    p.tilePrefix[0] = 0; p.tilePrefix[1] = (IN / 32) * (D / 32);
    wtrans_kernel<<<p.tilePrefix[1], 256, 0, stream>>>(p);
  }
  embed_conv<<<(SB * IN) / 256, 256, 0, stream>>>(h_in, ABUFp);
  gemm(ABUFp, WETp, be, OUTp, XBFp, SB, D, IN, IN, IN, D, 0, 0, 0, 0, 1, 1, 1 | 2 | 4 | 8);

  for (int li = 0; li < 4; ++li) {
    WPack p{};
    int nt = 0, id = 0;
    auto addw = [&](const float* s, u16* d, int K, int N) {
      p.src[id] = s; p.dst[id] = d; p.K[id] = K; p.N[id] = N;
      p.tilePrefix[id] = nt; nt += (K / 32) * (N / 32); ++id;
    };
    addw(Wq + li * DD, WTp + 0 * DD, D, D);
    addw(Wk + li * DD, WTp + 1 * DD, D, D);
    addw(Wv + li * DD, WTp + 2 * DD, D, D);
    addw(Wr + li * DD, WTp + 3 * DD, D, D);
    addw(Wo + li * DD, WTp + 4 * DD, D, D);
    addw(gWr + (li * 2 + 0) * DD, WTp + 5 * DD, D, D);
    addw(gWz + (li * 2 + 0) * DD, WTp + 6 * DD, D, D);
    addw(gWg + (li * 2 + 0) * DD, WTp + 7 * DD, D, D);
    addw(gUr + (li * 2 + 0) * DD, WTp + 8 * DD, D, D);
    addw(gUz + (li * 2 + 0) * DD, WTp + 9 * DD, D, D);
    addw(gUg + (li * 2 + 0) * DD, WTp + 10 * DD, D, D);
    addw(gWr + (li * 2 + 1) * DD, WTp + 11 * DD, D, D);
    addw(gWz + (li * 2 + 1) * DD, WTp + 12 * DD, D, D);
    addw(gWg + (li * 2 + 1) * DD, WTp + 13 * DD, D, D);
    addw(gUr + (li * 2 + 1) * DD, WTp + 14 * DD, D, D);
    addw(gUz + (li * 2 + 1) * DD, WTp + 15 * DD, D, D);
    addw(gUg + (li * 2 + 1) * DD, WTp + 16 * DD, D, D);
    addw(fW1 + li * (long long)D * 4096, WTp + 17 * DD, D, 4096);
    addw(fW2 + li * (long long)4096 * D, WTp + 21 * DD, 4096, D);
    p.tilePrefix[id] = nt; p.nm = id;
    wtrans_kernel<<<nt, 256, 0, stream>>>(p);

    ln_kernel<<<FB, 256, 0, stream>>>(memory + (long long)li * MM * B * D, OUTp, MM * B,
                                      ln1s + li * D, ln1b + li * D, KNp);
    const u16* QN = KNp + (size_t)MM * B * D;

    // ---- projections + attention prep ----
    gemm(QN, WTp + 0 * DD, bq + li * D, Qf, nullptr, SB, D, D, D, D, D, 0, 0, 0, 0, 1, 1, 2 | 4);
    prep_q<<<(B * H * S * 64) / 256, 256, 0, stream>>>(Qf, QBp);
    gemm(KNp, WTp + 1 * DD, bk + li * D, Qf, nullptr, FB, D, D, D, D, D, 0, 0, 0, 0, 1, 1, 2 | 4);
    prep_k<<<(B * H * F * 64) / 256, 256, 0, stream>>>(Qf, KBHp);
    uk_kernel<<<(B * H * F) / 256, 256, 0, stream>>>(KBHp, uu + li * H * 64, uKp);
    gemm(KNp, WTp + 2 * DD, bv + li * D, Qf, nullptr, FB, D, D, D, D, D, 0, 0, 0, 0, 1, 1, 2 | 4);
    prep_vt<<<dim3(F / 64, B * H), 256, 0, stream>>>(Qf, VTp);
    gemm(PEBp, WTp + 3 * DD, br + li * D, Qf, nullptr, F, D, D, D, D, D, 0, 0, 0, 0, 1, 1, 2 | 4);
    prep_rh<<<(H * F * 64) / 256, 256, 0, stream>>>(Qf, RHp);
    vbr_kernel<<<(H * F) / 256, 256, 0, stream>>>(RHp, vbp + li * H * 64, vbRp);

    // ---- fused attention ----
    fused_attn<<<dim3(S / 64, B * H), 256, 0, stream>>>(QBp, KBHp, VTp, RHp, uKp, vbRp, YBFAp);

    // ---- output projection: y = gelu(attn @ Wo + bo) ----
    gemm(YBFAp, WTp + 4 * DD, bo + li * D, nullptr, YBFp, SB, D, D, D, D, D, 0, 0, 0, 0, 1, 1, 1 | 2 | 8);

    // ---- GRU1 ----
    gemm(YBFp, WTp + 5 * DD, nullptr, T1, nullptr, SB, 3 * D, D, D, D, 3 * D, 0, 0, 0, 0, 1, 1, 4);
    gemm(XBFp, WTp + 8 * DD, nullptr, T2, nullptr, SB, 2 * D, D, D, D, 2 * D, 0, 0, 0, 0, 1, 1, 4);
    gru_elemA<<<(SB * D / 4) / 256, 256, 0, stream>>>(T1, T2, OUTp, ABUFp);
    gemm(ABUFp, WTp + 10 * DD, nullptr, TGp, nullptr, SB, D, D, D, D, D, 0, 0, 0, 0, 1, 1, 4);
    gru_elemB<<<(SB * D / 4) / 256, 256, 0, stream>>>(T1, T2, TGp, OUTp, OUT1p, XBFp);

    // ---- FFN ----
    ln_kernel<<<SB, 256, 0, stream>>>(OUT1p, OUT1p, SB, ln2s + li * D, ln2b + li * D, ABUFp);
    gemm(ABUFp, WTp + 17 * DD, fb1 + li * 4096, nullptr, FFNBp, SB, 4096, D, D, D, 4096,
         0, 0, 0, 0, 1, 1, 1 | 2 | 8);
    gemm(FFNBp, WTp + 21 * DD, fb2 + li * D, nullptr, YBFp, SB, D, 4096, 4096, 4096, D,
         0, 0, 0, 0, 1, 1, 1 | 2 | 8);

    // ---- GRU2 ----
    gemm(YBFp, WTp + 11 * DD, nullptr, T1, nullptr, SB, 3 * D, D, D, D, 3 * D, 0, 0, 0, 0, 1, 1, 4);
    gemm(XBFp, WTp + 14 * DD, nullptr, T2, nullptr, SB, 2 * D, D, D, D, 2 * D, 0, 0, 0, 0, 1, 1, 4);
    gru_elemA<<<(SB * D / 4) / 256, 256, 0, stream>>>(T1, T2, OUT1p, ABUFp);
    gemm(ABUFp, WTp + 16 * DD, nullptr, TGp, nullptr, SB, D, D, D, D, D, 0, 0, 0, 0, 1, 1, 4);
    gru_elemB<<<(SB * D / 4) / 256, 256, 0, stream>>>(T1, T2, TGp, OUT1p, OUTp, XBFp);
  }

  out_transpose<<<(SB * D / 4) / 256, 256, 0, stream>>>(OUTp, (float*)d_out);
}

// Round 4
// 3378.056 us; speedup vs baseline: 1.6166x; 1.0478x over previous
//
#include <hip/hip_runtime.h>

typedef unsigned short u16;
typedef unsigned long long u64;
typedef __attribute__((ext_vector_type(8))) short bf16x8;
typedef __attribute__((ext_vector_type(4))) float f32x4;

#define DEVI __device__ __forceinline__

DEVI u16 f2b(float f) {
  unsigned u = __float_as_uint(f);
  u += 0x7fffu + ((u >> 16) & 1u);
  return (u16)(u >> 16);
}
DEVI float b2f(u16 v) { return __uint_as_float((unsigned)v << 16); }
DEVI float tanh_f(float x) {
  float xc = fminf(fmaxf(x, -15.f), 15.f);
  float e = __expf(2.f * xc);
  return (e - 1.f) / (e + 1.f);
}
DEVI float gelu_f(float x) {
  float u = 0.7978845608028654f * x * (1.f + 0.044715f * x * x);
  return 0.5f * x * (1.f + tanh_f(u));
}
DEVI float sigm_f(float x) { return 1.f / (1.f + __expf(-x)); }

DEVI void gload16(const void* g, void* l) {
  __builtin_amdgcn_global_load_lds((__attribute__((address_space(1))) void*)g,
                                   (__attribute__((address_space(3))) void*)l, 16, 0, 0);
}

// ---------------------------------------------------------------------------
// Generic batched GEMM:  C[z] = act(A[z] (MxK) @ Bt[z]^T + bias), Bt is (N x K).
// flags: 1=gelu, 2=bias, 4=store f32, 8=store bf16,
//        16=perm head-layout [b][h][seq][64] (row=s*8+b, col=h*64+d, seq=ldC),
//        32=perm R-layout    [h][c][64]     (row=c, col=h*64+d)
// T3-minimum 2-phase pipeline (double-buffered LDS, stage(t+1) before compute(t)).
// ---------------------------------------------------------------------------
__global__ __launch_bounds__(256) void gemm_bt(
    const u16* __restrict__ A, const u16* __restrict__ Bt,
    const float* __restrict__ bias, float* __restrict__ C32, u16* __restrict__ C16,
    int M, int N, int K, int ldA, int ldB, int ldC,
    long long sA, long long sBb, long long sBh, long long sC, int nH, int flags)
{
  __shared__ __align__(16) u16 Sm[2][256 * 64];
  const int z = blockIdx.z;
  const int zb = z / nH, zh = z - zb * nH;
  A  += (long long)z * sA;
  Bt += (long long)zb * sBb + (long long)zh * sBh;
  const long long cOff = (long long)z * sC;
  const int m0 = blockIdx.x * 128, n0 = blockIdx.y * 128;
  const int t = threadIdx.x, lane = t & 63;
  const int wm = ((t >> 7) & 1) * 64, wn = ((t >> 6) & 1) * 64;

  f32x4 acc[4][4];
#pragma unroll
  for (int i = 0; i < 4; ++i)
#pragma unroll
    for (int j = 0; j < 4; ++j) { f32x4 zz = {0.f, 0.f, 0.f, 0.f}; acc[i][j] = zz; }

  auto stage = [&](int buf, int k0) {
#pragma unroll
    for (int r = 0; r < 4; ++r) {
      const int c = r * 256 + t;
      const int row = c >> 3;
      const int col = (c & 7) << 3;
      int ga = m0 + row; if (ga >= M) ga = M - 1;
      gload16(A + (long long)ga * ldA + (k0 + col),
              &Sm[buf][(size_t)(r * 256 + (t & 192)) * 8]);
      int gb = n0 + row; if (gb >= N) gb = N - 1;
      gload16(Bt + (long long)gb * ldB + (k0 + col),
              &Sm[buf][(size_t)(1024 + r * 256 + (t & 192)) * 8]);
    }
  };

  auto compute = [&](int buf) {
    const u16* As = &Sm[buf][0];
    const u16* Bs = &Sm[buf][128 * 64];
#pragma unroll
    for (int ks = 0; ks < 2; ++ks) {
      const int ko = ks * 32 + ((lane >> 4) << 3);
      bf16x8 af[4], bfv[4];
#pragma unroll
      for (int i = 0; i < 4; ++i)
        af[i] = *(const bf16x8*)&As[(wm + i * 16 + (lane & 15)) * 64 + ko];
#pragma unroll
      for (int i = 0; i < 4; ++i)
        bfv[i] = *(const bf16x8*)&Bs[(wn + i * 16 + (lane & 15)) * 64 + ko];
#pragma unroll
      for (int mi = 0; mi < 4; ++mi)
#pragma unroll
        for (int ni = 0; ni < 4; ++ni)
          acc[mi][ni] = __builtin_amdgcn_mfma_f32_16x16x32_bf16(af[mi], bfv[ni], acc[mi][ni], 0, 0, 0);
    }
  };

  stage(0, 0);
  __syncthreads();
  int cur = 0;
  for (int k0 = 64; k0 < K; k0 += 64) {
    stage(cur ^ 1, k0);
    compute(cur);
    __syncthreads();
    cur ^= 1;
  }
  compute(cur);

  const int cb = n0 + wn + (lane & 15);
  const int rb = m0 + wm + ((lane >> 4) << 2);
#pragma unroll
  for (int ni = 0; ni < 4; ++ni) {
    const int col = cb + ni * 16;
    if (col >= N) continue;
    const float bv = (flags & 2) ? bias[col] : 0.f;
#pragma unroll
    for (int mi = 0; mi < 4; ++mi) {
#pragma unroll
      for (int q = 0; q < 4; ++q) {
        const int row = rb + mi * 16 + q;
        if (row >= M) continue;
        float x = acc[mi][ni][q] + bv;
        if (flags & 1) x = gelu_f(x);
        long long o;
        if (flags & 16)
          o = ((long long)((row & 7) * 16 + (col >> 6)) * ldC + (row >> 3)) * 64 + (col & 63);
        else if (flags & 32)
          o = ((long long)(col >> 6) * 1024 + row) * 64 + (col & 63);
        else
          o = cOff + (long long)row * ldC + col;
        if (flags & 4) C32[o] = x;
        if (flags & 8) C16[o] = f2b(x);
      }
    }
  }
}

// ---------------------------------------------------------------------------
// Fused rel-pos attention (flash-style). Block = 64 q-rows of one (b,h).
// scores(i,j) = (q_i·k_j + u·k_j + q_i·r_{j-i+511} + vb·r_{j-i+511})/8, masked
// j-i>512; online softmax; O = P V. 1D grid with T1 bijective XCD swizzle so
// all 8 i-blocks of one bh land on the same XCD (K/V/R L2 reuse).
// PB band is stored transposed (PBT[c][di]) so each wave writes packed u64.
// ---------------------------------------------------------------------------
__global__ __launch_bounds__(256) void fused_attn(
    const u16* __restrict__ Qb,   // [bh][s][64]
    const u16* __restrict__ Kb,   // [bh][f][64]
    const u16* __restrict__ Vt,   // [bh][d][1024]
    const u16* __restrict__ Rh,   // [h][c][64]
    const float* __restrict__ uK,  // [bh][f]
    const float* __restrict__ vbR, // [h][c]
    u16* __restrict__ Y)           // [s][b*1024 + h*64 + d]
{
  constexpr int F = 1024;
  const int bid = blockIdx.x;                 // 1024 blocks
  const int wk = (bid & 7) * 128 + (bid >> 3);  // XCD-bijective swizzle
  const int i0 = (wk & 7) * 64;
  const int bh = wk >> 3;
  const int h = bh & 15;

  __shared__ __align__(16) u16 Qs[64 * 64];
  __shared__ __align__(16) u16 Ks[64 * 64];
  __shared__ __align__(16) u16 Vs[64 * 64];
  __shared__ __align__(16) u16 Rs[2][64 * 64];
  __shared__ __align__(8) u16 PBT[128 * 68];      // pos band transposed [c][di]
  __shared__ __align__(16) u16 Ps[4][16][72];     // per-wave P tiles, padded
  __shared__ float uKs[64];
  __shared__ float vbRs[2][64];

  const int t = threadIdx.x;
  const int lane = t & 63;
  const int wq = t >> 6;           // wave id -> q-row block [16*wq, 16*wq+16)
  const int l15 = lane & 15, lhi = lane >> 4;

  const u16* Qg = Qb + ((size_t)bh * 512 + i0) * 64;
  const u16* Kg = Kb + (size_t)bh * F * 64;
  const u16* Vg = Vt + (size_t)bh * 64 * F;
  const u16* Rg = Rh + (size_t)h * F * 64;
  const float* uKg = uK + (size_t)bh * F;
  const float* vbRg = vbR + (size_t)h * F;

  auto stageQ = [&]() {
#pragma unroll
    for (int rnd = 0; rnd < 2; ++rnd) {
      const int idx = rnd * 256 + t;
      const int row = idx >> 3;
      const int gs = (idx & 7) ^ (row & 7);
      gload16(Qg + row * 64 + gs * 8, Qs + (size_t)(rnd * 256 + (t & 192)) * 8);
    }
  };
  auto stageK = [&](int j0) {
#pragma unroll
    for (int rnd = 0; rnd < 2; ++rnd) {
      const int idx = rnd * 256 + t;
      const int row = idx >> 3;
      const int gs = (idx & 7) ^ (row & 7);
      gload16(Kg + (j0 + row) * 64 + gs * 8, Ks + (size_t)(rnd * 256 + (t & 192)) * 8);
    }
  };
  auto stageV = [&](int j0) {
#pragma unroll
    for (int rnd = 0; rnd < 2; ++rnd) {
      const int idx = rnd * 256 + t;
      const int row = idx >> 3;
      const int gs = (idx & 7) ^ (row & 7);
      gload16(Vg + row * F + j0 + gs * 8, Vs + (size_t)(rnd * 256 + (t & 192)) * 8);
    }
  };
  auto stageR = [&](u16* dst, int cbase) {
#pragma unroll
    for (int rnd = 0; rnd < 2; ++rnd) {
      const int idx = rnd * 256 + t;
      const int row = idx >> 3;
      const int gs = (idx & 7) ^ (row & 7);
      int grow = cbase + row; if (grow > 1023) grow = 1023;
      gload16(Rg + grow * 64 + gs * 8, dst + (size_t)(rnd * 256 + (t & 192)) * 8);
    }
  };

  // prologue: Q tile + first R lo tile + vbR lo
  stageQ();
  const int c_lo0 = 448 - i0;  // >= 0 (i0 <= 448)
  stageR(Rs[0], c_lo0);
  if (t < 64) {
    int c = c_lo0 + t; if (c > 1023) c = 1023;
    vbRs[0][t] = vbRg[c];
  }

  f32x4 Oacc[4];
#pragma unroll
  for (int i = 0; i < 4; ++i) { f32x4 zz = {0.f, 0.f, 0.f, 0.f}; Oacc[i] = zz; }
  float mrow[4] = {-3.0e38f, -3.0e38f, -3.0e38f, -3.0e38f};
  float lrow[4] = {0.f, 0.f, 0.f, 0.f};

  const int nT = i0 / 64 + 9;
  for (int st = 0; st < nT; ++st) {
    const int j0 = st * 64;
    const int c_hi = j0 - i0 + 512;
    const bool lastT = (st == nT - 1);
    __syncthreads();   // A: previous compute done, safe to overwrite tiles
    stageK(j0);
    stageV(j0);
    if (!lastT) stageR(Rs[(st + 1) & 1], c_hi);
    if (t < 64) uKs[t] = uKg[j0 + t];
    else if (t < 128 && !lastT) {
      int c = c_hi + (t - 64); if (c > 1023) c = 1023;
      vbRs[(st + 1) & 1][t - 64] = vbRg[c];
    }
    __syncthreads();   // B: staged data visible (vmcnt drain)

    const u16* RsLo = Rs[st & 1];
    const u16* RsHi = Rs[(st + 1) & 1];
    const float* vLo = vbRs[st & 1];
    const float* vHi = vbRs[(st + 1) & 1];

    // ---- content + position-band MFMAs (shared A = q) ----
    f32x4 cacc[4], pbacc[8];
#pragma unroll
    for (int i = 0; i < 4; ++i) { f32x4 zz = {0.f, 0.f, 0.f, 0.f}; cacc[i] = zz; }
#pragma unroll
    for (int i = 0; i < 8; ++i) { f32x4 zz = {0.f, 0.f, 0.f, 0.f}; pbacc[i] = zz; }
    __builtin_amdgcn_s_setprio(1);
#pragma unroll
    for (int ks = 0; ks < 2; ++ks) {
      const int arow = wq * 16 + l15;
      const bf16x8 a = *(const bf16x8*)&Qs[arow * 64 + (((ks * 4 + lhi) ^ (arow & 7)) << 3)];
#pragma unroll
      for (int ni = 0; ni < 4; ++ni) {
        const int brow = ni * 16 + l15;
        const bf16x8 bk_ = *(const bf16x8*)&Ks[brow * 64 + (((ks * 4 + lhi) ^ (brow & 7)) << 3)];
        cacc[ni] = __builtin_amdgcn_mfma_f32_16x16x32_bf16(a, bk_, cacc[ni], 0, 0, 0);
      }
#pragma unroll
      for (int ni = 0; ni < 8; ++ni) {
        if (ni >= 4 && lastT) continue;   // hi band fully masked on last tile
        const int brow = (ni & 3) * 16 + l15;
        const u16* rt = (ni < 4) ? RsLo : RsHi;
        const bf16x8 br_ = *(const bf16x8*)&rt[brow * 64 + (((ks * 4 + lhi) ^ (brow & 7)) << 3)];
        pbacc[ni] = __builtin_amdgcn_mfma_f32_16x16x32_bf16(a, br_, pbacc[ni], 0, 0, 0);
      }
    }
    __builtin_amdgcn_s_setprio(0);

    // write PB band transposed (packed u64 per ni; own-wave rows only)
#pragma unroll
    for (int ni = 0; ni < 8; ++ni) {
      if (ni >= 4 && lastT) continue;
      u64 w = (u64)f2b(pbacc[ni][0]) | ((u64)f2b(pbacc[ni][1]) << 16) |
              ((u64)f2b(pbacc[ni][2]) << 32) | ((u64)f2b(pbacc[ni][3]) << 48);
      *(u64*)&PBT[(size_t)(ni * 16 + l15) * 68 + wq * 16 + lhi * 4] = w;
    }

    // ---- build scores ----
    const int lim = i0 - j0 + 512;
    float sc[4][4];
#pragma unroll
    for (int ni = 0; ni < 4; ++ni) {
      const int dj = ni * 16 + l15;
      const float uk = uKs[dj];
#pragma unroll
      for (int qq = 0; qq < 4; ++qq) {
        const int di = wq * 16 + lhi * 4 + qq;
        const int cc = dj - di + 63;                // [0,126]
        const float pb = b2f(PBT[(size_t)cc * 68 + di]);
        const float vr = (cc < 64) ? vLo[cc] : vHi[cc - 64];
        float s = (cacc[ni][qq] + uk + pb + vr) * 0.125f;
        if (dj - di > lim) s = -1e30f;
        sc[ni][qq] = s;
      }
    }

    // ---- online softmax (per wave; rows wave-exclusive) ----
    float nm[4], esc[4];
#pragma unroll
    for (int qq = 0; qq < 4; ++qq) {
      float r = fmaxf(fmaxf(sc[0][qq], sc[1][qq]), fmaxf(sc[2][qq], sc[3][qq]));
      r = fmaxf(r, __shfl_xor(r, 1));
      r = fmaxf(r, __shfl_xor(r, 2));
      r = fmaxf(r, __shfl_xor(r, 4));
      r = fmaxf(r, __shfl_xor(r, 8));
      nm[qq] = fmaxf(mrow[qq], r);
      esc[qq] = __expf(mrow[qq] - nm[qq]);
      mrow[qq] = nm[qq];
    }
    float ps[4][4];
    float rsum[4] = {0.f, 0.f, 0.f, 0.f};
#pragma unroll
    for (int ni = 0; ni < 4; ++ni)
#pragma unroll
      for (int qq = 0; qq < 4; ++qq) {
        float p = __expf(sc[ni][qq] - nm[qq]);
        ps[ni][qq] = p;
        rsum[qq] += p;
      }
#pragma unroll
    for (int qq = 0; qq < 4; ++qq) {
      float r = rsum[qq];
      r += __shfl_xor(r, 1);
      r += __shfl_xor(r, 2);
      r += __shfl_xor(r, 4);
      r += __shfl_xor(r, 8);
      lrow[qq] = lrow[qq] * esc[qq] + r;
    }
#pragma unroll
    for (int nd = 0; nd < 4; ++nd)
#pragma unroll
      for (int qq = 0; qq < 4; ++qq) Oacc[nd][qq] *= esc[qq];

    // ---- P -> LDS (bf16) -> PV MFMA ----
#pragma unroll
    for (int ni = 0; ni < 4; ++ni)
#pragma unroll
      for (int qq = 0; qq < 4; ++qq)
        Ps[wq][lhi * 4 + qq][ni * 16 + l15] = f2b(ps[ni][qq]);
    __builtin_amdgcn_s_setprio(1);
#pragma unroll
    for (int ks = 0; ks < 2; ++ks) {
      const bf16x8 pa = *(const bf16x8*)&Ps[wq][l15][ks * 32 + lhi * 8];
#pragma unroll
      for (int nd = 0; nd < 4; ++nd) {
        const int vrow = nd * 16 + l15;
        const bf16x8 vb_ = *(const bf16x8*)&Vs[vrow * 64 + (((ks * 4 + lhi) ^ (vrow & 7)) << 3)];
        Oacc[nd] = __builtin_amdgcn_mfma_f32_16x16x32_bf16(pa, vb_, Oacc[nd], 0, 0, 0);
      }
    }
    __builtin_amdgcn_s_setprio(0);
  }

  // epilogue: normalize and store
  float inv[4];
#pragma unroll
  for (int qq = 0; qq < 4; ++qq) inv[qq] = 1.f / lrow[qq];
  const int b = bh >> 4;
#pragma unroll
  for (int nd = 0; nd < 4; ++nd)
#pragma unroll
    for (int qq = 0; qq < 4; ++qq) {
      const int row = i0 + wq * 16 + lhi * 4 + qq;
      const int d = nd * 16 + l15;
      Y[(size_t)row * 8192 + b * 1024 + h * 64 + d] = f2b(Oacc[nd][qq] * inv[qq]);
    }
}

// ---------------------------------------------------------------------------
// rank-1 terms: uK[bh][f] = u[h]·K[bh][f][:],  vbR[h][c] = vb[h]·R[h][c][:]
// ---------------------------------------------------------------------------
__global__ __launch_bounds__(256) void uk_kernel(const u16* __restrict__ Kb,
                                                 const float* __restrict__ u,
                                                 float* __restrict__ uK)
{
  const long long idx = (long long)blockIdx.x * 256 + threadIdx.x;  // bh*F + f
  const int h = (int)((idx >> 10) & 15);
  const u16* k = Kb + idx * 64;
  const float* uh = u + h * 64;
  float s = 0.f;
#pragma unroll
  for (int j = 0; j < 8; ++j) {
    bf16x8 kv = *(const bf16x8*)&k[j * 8];
#pragma unroll
    for (int e = 0; e < 8; ++e) s += b2f((u16)kv[e]) * uh[j * 8 + e];
  }
  uK[idx] = s;
}

__global__ __launch_bounds__(256) void vbr_kernel(const u16* __restrict__ Rh,
                                                  const float* __restrict__ vb,
                                                  float* __restrict__ vbR)
{
  const long long idx = (long long)blockIdx.x * 256 + threadIdx.x;  // h*F + c
  const int h = (int)(idx >> 10);
  const u16* r = Rh + idx * 64;
  const float* vh = vb + h * 64;
  float s = 0.f;
#pragma unroll
  for (int j = 0; j < 8; ++j) {
    bf16x8 rv = *(const bf16x8*)&r[j * 8];
#pragma unroll
    for (int e = 0; e < 8; ++e) s += b2f((u16)rv[e]) * vh[j * 8 + e];
  }
  vbR[idx] = s;
}

// ---------------------------------------------------------------------------
// Weight transpose+convert: src (K x N) f32  ->  dst (N x K) bf16. Dims %32==0.
// ---------------------------------------------------------------------------
#define MAXW 20
struct WPack {
  const float* src[MAXW];
  u16* dst[MAXW];
  int K[MAXW], N[MAXW];
  int tilePrefix[MAXW + 1];
  int nm;
};

__global__ __launch_bounds__(256) void wtrans_kernel(WPack p) {
  int bid = blockIdx.x;
  int m = 0;
  while (m < p.nm && bid >= p.tilePrefix[m + 1]) ++m;
  if (m >= p.nm) return;
  const int lt = bid - p.tilePrefix[m];
  const int K = p.K[m], N = p.N[m];
  const int tN = N >> 5;
  const int kt = lt / tN, nt = lt - kt * tN;
  const int k0 = kt << 5, n0 = nt << 5;
  const float* src = p.src[m];
  u16* dst = p.dst[m];
  __shared__ float tile[32][33];
  const int t = threadIdx.x;
  const int r = t >> 3, c4 = (t & 7) << 2;
  float4 v = *(const float4*)&src[(size_t)(k0 + r) * N + n0 + c4];
  tile[r][c4 + 0] = v.x; tile[r][c4 + 1] = v.y; tile[r][c4 + 2] = v.z; tile[r][c4 + 3] = v.w;
  __syncthreads();
  u16 o0 = f2b(tile[c4 + 0][r]);
  u16 o1 = f2b(tile[c4 + 1][r]);
  u16 o2 = f2b(tile[c4 + 2][r]);
  u16 o3 = f2b(tile[c4 + 3][r]);
  u64 w = (u64)o0 | ((u64)o1 << 16) | ((u64)o2 << 32) | ((u64)o3 << 48);
  *(u64*)&dst[(size_t)(n0 + r) * K + k0 + c4] = w;
}

// ---------------------------------------------------------------------------
// LayerNorm over D=1024; rows [0,rowsMem) from Xmem, rest from Xout. bf16 out.
// ---------------------------------------------------------------------------
__global__ __launch_bounds__(256) void ln_kernel(
    const float* __restrict__ Xmem, const float* __restrict__ Xout, int rowsMem,
    const float* __restrict__ sc, const float* __restrict__ bi, u16* __restrict__ dst)
{
  const int row = blockIdx.x;
  const float* src = (row < rowsMem) ? (Xmem + (long long)row * 1024)
                                     : (Xout + (long long)(row - rowsMem) * 1024);
  const int t = threadIdx.x;
  float4 v = *(const float4*)&src[t * 4];
  float s1 = v.x + v.y + v.z + v.w;
  float s2 = v.x * v.x + v.y * v.y + v.z * v.z + v.w * v.w;
#pragma unroll
  for (int o = 32; o > 0; o >>= 1) { s1 += __shfl_down(s1, o); s2 += __shfl_down(s2, o); }
  __shared__ float red[8];
  const int wv = t >> 6;
  if ((t & 63) == 0) { red[wv * 2] = s1; red[wv * 2 + 1] = s2; }
  __syncthreads();
  s1 = red[0] + red[2] + red[4] + red[6];
  s2 = red[1] + red[3] + red[5] + red[7];
  const float mu = s1 * (1.f / 1024.f);
  const float var = s2 * (1.f / 1024.f) - mu * mu;
  const float rs = rsqrtf(var + 1e-5f);
  float vals[4] = {v.x, v.y, v.z, v.w};
  u16 o4[4];
#pragma unroll
  for (int j = 0; j < 4; ++j) {
    const int c = t * 4 + j;
    o4[j] = f2b((vals[j] - mu) * rs * sc[c] + bi[c]);
  }
  *(u64*)&dst[(long long)row * 1024 + t * 4] =
      (u64)o4[0] | ((u64)o4[1] << 16) | ((u64)o4[2] << 32) | ((u64)o4[3] << 48);
}

// ---------------------------------------------------------------------------
// small prep / elementwise kernels
// ---------------------------------------------------------------------------
__global__ __launch_bounds__(256) void prep_vt16(const u16* __restrict__ Vf, u16* __restrict__ VT)
{
  // Vf: [f*8+b][1024] bf16 (cols h*64+d) -> VT[bh][d][1024]
  const int f0 = blockIdx.x * 64;
  const int bh = blockIdx.y;
  const int b = bh >> 4, h = bh & 15;
  __shared__ u16 tl[64 * 64];
  const int t = threadIdx.x;
  {
    const int fr = t >> 2, c0 = (t & 3) * 16;
    const u16* src = Vf + ((size_t)(f0 + fr) * 8 + b) * 1024 + h * 64 + c0;
    *(bf16x8*)&tl[fr * 64 + c0] = *(const bf16x8*)src;
    *(bf16x8*)&tl[fr * 64 + c0 + 8] = *(const bf16x8*)(src + 8);
  }
  __syncthreads();
  {
    const int dr = t >> 2, c0 = (t & 3) * 16;
    u16* dst = VT + ((long long)bh * 64 + dr) * 1024 + f0 + c0;
#pragma unroll
    for (int j = 0; j < 16; ++j) dst[j] = tl[(c0 + j) * 64 + dr];
  }
}

__global__ __launch_bounds__(256) void pe_kernel(u16* __restrict__ PEB)
{
  const long long idx = (long long)blockIdx.x * 256 + threadIdx.x;  // F*D
  const int p = (int)(idx >> 10);
  const int d = idx & 1023;
  const int q = d & 511;
  const float inv = powf(10000.f, -(float)(2 * q) * (1.f / 1024.f));
  const float ang = (float)(1023 - p) * inv;
  PEB[idx] = f2b((d < 512) ? sinf(ang) : cosf(ang));
}

__global__ __launch_bounds__(256) void embed_conv(const float* __restrict__ h, u16* __restrict__ A)
{
  const long long idx = (long long)blockIdx.x * 256 + threadIdx.x;  // SB*IN
  const int c = idx & 127;
  const int r = (int)(idx >> 7);
  const int s = r >> 3, b = r & 7;
  A[idx] = f2b(h[(((long long)b * 512 + s) << 7) + c]);
}

__global__ __launch_bounds__(256) void gru_elemA(const float* __restrict__ T1, float* __restrict__ T2,
                                                 const float* __restrict__ X, u16* __restrict__ RXBF)
{
  const long long i4 = ((long long)blockIdx.x * 256 + threadIdx.x) * 4;  // SB*D
  const int row = (int)(i4 >> 10);
  const int c = i4 & 1023;
  const float* t1 = T1 + (long long)row * 3072 + c;
  float* t2 = T2 + (long long)row * 2048 + c;
  float4 ry = *(const float4*)t1;
  float4 zy = *(const float4*)(t1 + 1024);
  float4 rx = *(const float4*)t2;
  float4 zx = *(const float4*)(t2 + 1024);
  float4 x = *(const float4*)(X + i4);
  float rr[4], zz[4];
  rr[0] = sigm_f(ry.x + rx.x); rr[1] = sigm_f(ry.y + rx.y);
  rr[2] = sigm_f(ry.z + rx.z); rr[3] = sigm_f(ry.w + rx.w);
  zz[0] = sigm_f(zy.x + zx.x - 2.f); zz[1] = sigm_f(zy.y + zx.y - 2.f);
  zz[2] = sigm_f(zy.z + zx.z - 2.f); zz[3] = sigm_f(zy.w + zx.w - 2.f);
  u16 o4[4];
  o4[0] = f2b(rr[0] * x.x); o4[1] = f2b(rr[1] * x.y);
  o4[2] = f2b(rr[2] * x.z); o4[3] = f2b(rr[3] * x.w);
  *(u64*)&RXBF[i4] = (u64)o4[0] | ((u64)o4[1] << 16) | ((u64)o4[2] << 32) | ((u64)o4[3] << 48);
  float4 zo; zo.x = zz[0]; zo.y = zz[1]; zo.z = zz[2]; zo.w = zz[3];
  *(float4*)t2 = zo;
}

__global__ __launch_bounds__(256) void gru_elemB(const float* __restrict__ T1, const float* __restrict__ T2,
                                                 const float* __restrict__ TG, const float* __restrict__ X,
                                                 float* __restrict__ O, u16* __restrict__ XBF)
{
  const long long i4 = ((long long)blockIdx.x * 256 + threadIdx.x) * 4;
  const int row = (int)(i4 >> 10);
  const int c = i4 & 1023;
  float4 gy = *(const float4*)(T1 + (long long)row * 3072 + 2048 + c);
  float4 tt = *(const float4*)(TG + i4);
  float4 z = *(const float4*)(T2 + (long long)row * 2048 + c);
  float4 x = *(const float4*)(X + i4);
  float4 o;
  o.x = (1.f - z.x) * x.x + z.x * tanh_f(gy.x + tt.x);
  o.y = (1.f - z.y) * x.y + z.y * tanh_f(gy.y + tt.y);
  o.z = (1.f - z.z) * x.z + z.z * tanh_f(gy.z + tt.z);
  o.w = (1.f - z.w) * x.w + z.w * tanh_f(gy.w + tt.w);
  *(float4*)(O + i4) = o;
  u16 o4[4];
  o4[0] = f2b(o.x); o4[1] = f2b(o.y); o4[2] = f2b(o.z); o4[3] = f2b(o.w);
  *(u64*)&XBF[i4] = (u64)o4[0] | ((u64)o4[1] << 16) | ((u64)o4[2] << 32) | ((u64)o4[3] << 48);
}

__global__ __launch_bounds__(256) void out_transpose(const float* __restrict__ O, float* __restrict__ dst)
{
  const long long i4 = ((long long)blockIdx.x * 256 + threadIdx.x) * 4;
  const int d = i4 & 1023;
  const int r = (int)(i4 >> 10);
  const int s = r >> 3, b = r & 7;
  float4 v = *(const float4*)(O + i4);
  *(float4*)&dst[(((long long)b * 512 + s) << 10) + d] = v;
}

// ---------------------------------------------------------------------------
extern "C" void kernel_launch(void* const* d_in, const int* in_sizes, int n_in,
                              void* d_out, int out_size, void* d_ws, size_t ws_size,
                              hipStream_t stream)
{
  (void)in_sizes; (void)n_in; (void)out_size; (void)ws_size;
  const float* h_in   = (const float*)d_in[0];
  const float* memory = (const float*)d_in[1];
  const float* We     = (const float*)d_in[2];
  const float* be     = (const float*)d_in[3];
  const float* ln1s   = (const float*)d_in[4];
  const float* ln1b   = (const float*)d_in[5];
  const float* ln2s   = (const float*)d_in[6];
  const float* ln2b   = (const float*)d_in[7];
  const float* Wq     = (const float*)d_in[8];
  const float* bq     = (const float*)d_in[9];
  const float* Wk     = (const float*)d_in[10];
  const float* bk     = (const float*)d_in[11];
  const float* Wv     = (const float*)d_in[12];
  const float* bv     = (const float*)d_in[13];
  const float* Wr     = (const float*)d_in[14];
  const float* br     = (const float*)d_in[15];
  const float* Wo     = (const float*)d_in[16];
  const float* bo     = (const float*)d_in[17];
  const float* uu     = (const float*)d_in[18];
  const float* vbp    = (const float*)d_in[19];
  const float* gWr    = (const float*)d_in[20];
  const float* gUr    = (const float*)d_in[21];
  const float* gWz    = (const float*)d_in[22];
  const float* gUz    = (const float*)d_in[23];
  const float* gWg    = (const float*)d_in[24];
  const float* gUg    = (const float*)d_in[25];
  const float* fW1    = (const float*)d_in[26];
  const float* fb1    = (const float*)d_in[27];
  const float* fW2    = (const float*)d_in[28];
  const float* fb2    = (const float*)d_in[29];

  constexpr int S = 512, MM = 512, B = 8, D = 1024, H = 16, IN = 128, F = 1024;
  constexpr int SB = 4096, FB = 8192;
  constexpr long long DD = (long long)D * D;

  char* ws = (char*)d_ws;
  size_t off = 0;
  auto alloc = [&](size_t bytes) -> size_t {
    size_t o = off; off = (off + bytes + 255) & ~(size_t)255; return o;
  };
  const size_t oWT   = alloc((size_t)25 * DD * 2);
  const size_t oWET  = alloc((size_t)D * IN * 2);
  const size_t oPEB  = alloc((size_t)F * D * 2);
  const size_t oOUT  = alloc((size_t)SB * D * 4);
  const size_t oOUT1 = alloc((size_t)SB * D * 4);
  const size_t oXBF  = alloc((size_t)SB * D * 2);
  const size_t oYBF  = alloc((size_t)SB * D * 2);
  const size_t oYBFA = alloc((size_t)SB * D * 2);
  const size_t oABUF = alloc((size_t)SB * D * 2);
  const size_t oKN   = alloc((size_t)FB * D * 2);
  const size_t oQB   = alloc((size_t)B * H * S * 64 * 2);
  const size_t oKBH  = alloc((size_t)B * H * F * 64 * 2);
  const size_t oVT   = alloc((size_t)B * H * F * 64 * 2);
  const size_t oRH   = alloc((size_t)H * F * 64 * 2);
  const size_t oUK   = alloc((size_t)B * H * F * 4);
  const size_t oVBR  = alloc((size_t)H * F * 4);
  const size_t oUNI  = off;

  u16* WTp   = (u16*)(ws + oWT);
  u16* WETp  = (u16*)(ws + oWET);
  u16* PEBp  = (u16*)(ws + oPEB);
  float* OUTp  = (float*)(ws + oOUT);
  float* OUT1p = (float*)(ws + oOUT1);
  u16* XBFp  = (u16*)(ws + oXBF);
  u16* YBFp  = (u16*)(ws + oYBF);
  u16* YBFAp = (u16*)(ws + oYBFA);
  u16* ABUFp = (u16*)(ws + oABUF);
  u16* KNp   = (u16*)(ws + oKN);
  u16* QBp   = (u16*)(ws + oQB);
  u16* KBHp  = (u16*)(ws + oKBH);
  u16* VTp   = (u16*)(ws + oVT);
  u16* RHp   = (u16*)(ws + oRH);
  float* uKp  = (float*)(ws + oUK);
  float* vbRp = (float*)(ws + oVBR);
  u16* VF16p  = (u16*)(ws + oUNI);
  float* T1   = (float*)(ws + oUNI);
  float* T2   = (float*)(ws + oUNI + (size_t)SB * 3 * D * 4);
  float* TGp  = (float*)(ws + oUNI + (size_t)SB * 5 * D * 4);
  u16* FFNBp  = (u16*)(ws + oUNI);

  auto gemm = [&](const u16* A, const u16* Bt, const float* bias, float* C32, u16* C16,
                  int M, int N, int K, int ldA, int ldB, int ldC,
                  long long sA, long long sBb, long long sBh, long long sC, int nH, int Z,
                  int flags) {
    dim3 grid((M + 127) / 128, (N + 127) / 128, Z);
    gemm_bt<<<grid, 256, 0, stream>>>(A, Bt, bias, C32, C16, M, N, K, ldA, ldB, ldC,
                                      sA, sBb, sBh, sC, nH, flags);
  };

  pe_kernel<<<(F * D) / 256, 256, 0, stream>>>(PEBp);
  {
    WPack p{};
    p.nm = 1; p.src[0] = We; p.dst[0] = WETp; p.K[0] = IN; p.N[0] = D;
    p.tilePrefix[0] = 0; p.tilePrefix[1] = (IN / 32) * (D / 32);
    wtrans_kernel<<<p.tilePrefix[1], 256, 0, stream>>>(p);
  }
  embed_conv<<<(SB * IN) / 256, 256, 0, stream>>>(h_in, ABUFp);
  gemm(ABUFp, WETp, be, OUTp, XBFp, SB, D, IN, IN, IN, D, 0, 0, 0, 0, 1, 1, 1 | 2 | 4 | 8);

  for (int li = 0; li < 4; ++li) {
    WPack p{};
    int nt = 0, id = 0;
    auto addw = [&](const float* s, u16* d, int K, int N) {
      p.src[id] = s; p.dst[id] = d; p.K[id] = K; p.N[id] = N;
      p.tilePrefix[id] = nt; nt += (K / 32) * (N / 32); ++id;
    };
    addw(Wq + li * DD, WTp + 0 * DD, D, D);
    addw(Wk + li * DD, WTp + 1 * DD, D, D);
    addw(Wv + li * DD, WTp + 2 * DD, D, D);
    addw(Wr + li * DD, WTp + 3 * DD, D, D);
    addw(Wo + li * DD, WTp + 4 * DD, D, D);
    addw(gWr + (li * 2 + 0) * DD, WTp + 5 * DD, D, D);
    addw(gWz + (li * 2 + 0) * DD, WTp + 6 * DD, D, D);
    addw(gWg + (li * 2 + 0) * DD, WTp + 7 * DD, D, D);
    addw(gUr + (li * 2 + 0) * DD, WTp + 8 * DD, D, D);
    addw(gUz + (li * 2 + 0) * DD, WTp + 9 * DD, D, D);
    addw(gUg + (li * 2 + 0) * DD, WTp + 10 * DD, D, D);
    addw(gWr + (li * 2 + 1) * DD, WTp + 11 * DD, D, D);
    addw(gWz + (li * 2 + 1) * DD, WTp + 12 * DD, D, D);
    addw(gWg + (li * 2 + 1) * DD, WTp + 13 * DD, D, D);
    addw(gUr + (li * 2 + 1) * DD, WTp + 14 * DD, D, D);
    addw(gUz + (li * 2 + 1) * DD, WTp + 15 * DD, D, D);
    addw(gUg + (li * 2 + 1) * DD, WTp + 16 * DD, D, D);
    addw(fW1 + li * (long long)D * 4096, WTp + 17 * DD, D, 4096);
    addw(fW2 + li * (long long)4096 * D, WTp + 21 * DD, 4096, D);
    p.tilePrefix[id] = nt; p.nm = id;
    wtrans_kernel<<<nt, 256, 0, stream>>>(p);

    ln_kernel<<<FB, 256, 0, stream>>>(memory + (long long)li * MM * B * D, OUTp, MM * B,
                                      ln1s + li * D, ln1b + li * D, KNp);
    const u16* QN = KNp + (size_t)MM * B * D;

    // ---- projections: direct head-layout bf16 epilogues ----
    gemm(QN, WTp + 0 * DD, bq + li * D, nullptr, QBp, SB, D, D, D, D, /*seq*/ S,
         0, 0, 0, 0, 1, 1, 2 | 8 | 16);
    gemm(KNp, WTp + 1 * DD, bk + li * D, nullptr, KBHp, FB, D, D, D, D, /*seq*/ F,
         0, 0, 0, 0, 1, 1, 2 | 8 | 16);
    uk_kernel<<<(B * H * F) / 256, 256, 0, stream>>>(KBHp, uu + li * H * 64, uKp);
    gemm(KNp, WTp + 2 * DD, bv + li * D, nullptr, VF16p, FB, D, D, D, D, D,
         0, 0, 0, 0, 1, 1, 2 | 8);
    prep_vt16<<<dim3(F / 64, B * H), 256, 0, stream>>>(VF16p, VTp);
    gemm(PEBp, WTp + 3 * DD, br + li * D, nullptr, RHp, F, D, D, D, D, D,
         0, 0, 0, 0, 1, 1, 2 | 8 | 32);
    vbr_kernel<<<(H * F) / 256, 256, 0, stream>>>(RHp, vbp + li * H * 64, vbRp);

    // ---- fused attention ----
    fused_attn<<<dim3((S / 64) * B * H), 256, 0, stream>>>(QBp, KBHp, VTp, RHp, uKp, vbRp, YBFAp);

    // ---- output projection: y = gelu(attn @ Wo + bo) ----
    gemm(YBFAp, WTp + 4 * DD, bo + li * D, nullptr, YBFp, SB, D, D, D, D, D, 0, 0, 0, 0, 1, 1, 1 | 2 | 8);

    // ---- GRU1 ----
    gemm(YBFp, WTp + 5 * DD, nullptr, T1, nullptr, SB, 3 * D, D, D, D, 3 * D, 0, 0, 0, 0, 1, 1, 4);
    gemm(XBFp, WTp + 8 * DD, nullptr, T2, nullptr, SB, 2 * D, D, D, D, 2 * D, 0, 0, 0, 0, 1, 1, 4);
    gru_elemA<<<(SB * D / 4) / 256, 256, 0, stream>>>(T1, T2, OUTp, ABUFp);
    gemm(ABUFp, WTp + 10 * DD, nullptr, TGp, nullptr, SB, D, D, D, D, D, 0, 0, 0, 0, 1, 1, 4);
    gru_elemB<<<(SB * D / 4) / 256, 256, 0, stream>>>(T1, T2, TGp, OUTp, OUT1p, XBFp);

    // ---- FFN ----
    ln_kernel<<<SB, 256, 0, stream>>>(OUT1p, OUT1p, SB, ln2s + li * D, ln2b + li * D, ABUFp);
    gemm(ABUFp, WTp + 17 * DD, fb1 + li * 4096, nullptr, FFNBp, SB, 4096, D, D, D, 4096,
         0, 0, 0, 0, 1, 1, 1 | 2 | 8);
    gemm(FFNBp, WTp + 21 * DD, fb2 + li * D, nullptr, YBFp, SB, D, 4096, 4096, 4096, D,
         0, 0, 0, 0, 1, 1, 1 | 2 | 8);

    // ---- GRU2 ----
    gemm(YBFp, WTp + 11 * DD, nullptr, T1, nullptr, SB, 3 * D, D, D, D, 3 * D, 0, 0, 0, 0, 1, 1, 4);
    gemm(XBFp, WTp + 14 * DD, nullptr, T2, nullptr, SB, 2 * D, D, D, D, 2 * D, 0, 0, 0, 0, 1, 1, 4);
    gru_elemA<<<(SB * D / 4) / 256, 256, 0, stream>>>(T1, T2, OUT1p, ABUFp);
    gemm(ABUFp, WTp + 16 * DD, nullptr, TGp, nullptr, SB, D, D, D, D, D, 0, 0, 0, 0, 1, 1, 4);
    gru_elemB<<<(SB * D / 4) / 256, 256, 0, stream>>>(T1, T2, TGp, OUT1p, OUTp, XBFp);
  }

  out_transpose<<<(SB * D / 4) / 256, 256, 0, stream>>>(OUTp, (float*)d_out);
}

// Round 5
// 3140.790 us; speedup vs baseline: 1.7388x; 1.0755x over previous
//
#include <hip/hip_runtime.h>

typedef unsigned short u16;
typedef unsigned long long u64;
typedef __attribute__((ext_vector_type(8))) short bf16x8;
typedef __attribute__((ext_vector_type(4))) float f32x4;

#define DEVI __device__ __forceinline__

DEVI u16 f2b(float f) {
  unsigned u = __float_as_uint(f);
  u += 0x7fffu + ((u >> 16) & 1u);
  return (u16)(u >> 16);
}
DEVI float b2f(u16 v) { return __uint_as_float((unsigned)v << 16); }
DEVI float tanh_f(float x) {
  float xc = fminf(fmaxf(x, -15.f), 15.f);
  float e = __expf(2.f * xc);
  return (e - 1.f) / (e + 1.f);
}
DEVI float gelu_f(float x) {
  float u = 0.7978845608028654f * x * (1.f + 0.044715f * x * x);
  return 0.5f * x * (1.f + tanh_f(u));
}
DEVI float sigm_f(float x) { return 1.f / (1.f + __expf(-x)); }

DEVI void gload16(const void* g, void* l) {
  __builtin_amdgcn_global_load_lds((__attribute__((address_space(1))) void*)g,
                                   (__attribute__((address_space(3))) void*)l, 16, 0, 0);
}

// ---------------------------------------------------------------------------
// Generic batched GEMM:  C[z] = act(A[z] (MxK) @ Bt[z]^T + bias), Bt is (N x K).
// flags: 1=gelu, 2=bias, 4=store f32, 8=store bf16,
//        16=perm head-layout [b][h][seq][64] (row=s*8+b, col=h*64+d, seq=ldC),
//        32=perm R-layout    [h][c][64]     (row=c, col=h*64+d)
// Template BN: 128 (tile 128x128, LDS 64KB, 2 blk/CU) or 64 (tile 128x64,
// LDS 48KB, 3 blk/CU -> more co-resident blocks for small-N shapes).
// ---------------------------------------------------------------------------
template <int BN>
__global__ __launch_bounds__(256) void gemm_bt(
    const u16* __restrict__ A, const u16* __restrict__ Bt,
    const float* __restrict__ bias, float* __restrict__ C32, u16* __restrict__ C16,
    int M, int N, int K, int ldA, int ldB, int ldC,
    long long sA, long long sBb, long long sBh, long long sC, int nH, int flags)
{
  constexpr int NF = BN / 32;            // N fragments per wave
  __shared__ __align__(16) u16 Sm[2][(128 + BN) * 64];
  const int z = blockIdx.z;
  const int zb = z / nH, zh = z - zb * nH;
  A  += (long long)z * sA;
  Bt += (long long)zb * sBb + (long long)zh * sBh;
  const long long cOff = (long long)z * sC;
  const int m0 = blockIdx.x * 128, n0 = blockIdx.y * BN;
  const int t = threadIdx.x, lane = t & 63;
  const int wm = ((t >> 7) & 1) * 64, wn = ((t >> 6) & 1) * (BN / 2);

  f32x4 acc[4][NF];
#pragma unroll
  for (int i = 0; i < 4; ++i)
#pragma unroll
    for (int j = 0; j < NF; ++j) { f32x4 zz = {0.f, 0.f, 0.f, 0.f}; acc[i][j] = zz; }

  auto stage = [&](int buf, int k0) {
#pragma unroll
    for (int r = 0; r < 4; ++r) {
      const int c = r * 256 + t;
      const int row = c >> 3;
      const int col = (c & 7) << 3;
      int ga = m0 + row; if (ga >= M) ga = M - 1;
      gload16(A + (long long)ga * ldA + (k0 + col),
              &Sm[buf][(size_t)(r * 256 + (t & 192)) * 8]);
    }
#pragma unroll
    for (int r = 0; r < BN / 32; ++r) {
      const int c = r * 256 + t;
      const int row = c >> 3;
      const int col = (c & 7) << 3;
      int gb = n0 + row; if (gb >= N) gb = N - 1;
      gload16(Bt + (long long)gb * ldB + (k0 + col),
              &Sm[buf][(size_t)(1024 + r * 256 + (t & 192)) * 8]);
    }
  };

  auto compute = [&](int buf) {
    const u16* As = &Sm[buf][0];
    const u16* Bs = &Sm[buf][128 * 64];
#pragma unroll
    for (int ks = 0; ks < 2; ++ks) {
      const int ko = ks * 32 + ((lane >> 4) << 3);
      bf16x8 af[4], bfv[NF];
#pragma unroll
      for (int i = 0; i < 4; ++i)
        af[i] = *(const bf16x8*)&As[(wm + i * 16 + (lane & 15)) * 64 + ko];
#pragma unroll
      for (int i = 0; i < NF; ++i)
        bfv[i] = *(const bf16x8*)&Bs[(wn + i * 16 + (lane & 15)) * 64 + ko];
#pragma unroll
      for (int mi = 0; mi < 4; ++mi)
#pragma unroll
        for (int ni = 0; ni < NF; ++ni)
          acc[mi][ni] = __builtin_amdgcn_mfma_f32_16x16x32_bf16(af[mi], bfv[ni], acc[mi][ni], 0, 0, 0);
    }
  };

  stage(0, 0);
  __syncthreads();
  int cur = 0;
  for (int k0 = 64; k0 < K; k0 += 64) {
    stage(cur ^ 1, k0);
    compute(cur);
    __syncthreads();
    cur ^= 1;
  }
  compute(cur);

  const int cb = n0 + wn + (lane & 15);
  const int rb = m0 + wm + ((lane >> 4) << 2);
#pragma unroll
  for (int ni = 0; ni < NF; ++ni) {
    const int col = cb + ni * 16;
    if (col >= N) continue;
    const float bv = (flags & 2) ? bias[col] : 0.f;
#pragma unroll
    for (int mi = 0; mi < 4; ++mi) {
#pragma unroll
      for (int q = 0; q < 4; ++q) {
        const int row = rb + mi * 16 + q;
        if (row >= M) continue;
        float x = acc[mi][ni][q] + bv;
        if (flags & 1) x = gelu_f(x);
        long long o;
        if (flags & 16)
          o = ((long long)((row & 7) * 16 + (col >> 6)) * ldC + (row >> 3)) * 64 + (col & 63);
        else if (flags & 32)
          o = ((long long)(col >> 6) * 1024 + row) * 64 + (col & 63);
        else
          o = cOff + (long long)row * ldC + col;
        if (flags & 4) C32[o] = x;
        if (flags & 8) C16[o] = f2b(x);
      }
    }
  }
}

// ---------------------------------------------------------------------------
// Fused rel-pos attention (flash-style). Block = 64 q-rows of one (b,h).
// QU = q+u, QV = q+vb precomputed, so scores = (QU·k + QV·r_{j-i+511})/8.
// Sliding-window band reuse: tile st's hi R-band == tile st+1's lo band, so
// only the NEW hi band is MFMA'd per tile; transposed band values rotate
// through PBT[2] (wave-local columns, no cross-wave sync needed).
// ---------------------------------------------------------------------------
__global__ __launch_bounds__(256) void fused_attn(
    const u16* __restrict__ Qu,   // [b][h][s][64]
    const u16* __restrict__ Qv,   // [b][h][s][64]
    const u16* __restrict__ Kb,   // [b][h][f][64]
    const u16* __restrict__ Vt,   // [bh][d][1024]
    const u16* __restrict__ Rh,   // [h][c][64]
    u16* __restrict__ Y)           // [s][b*1024 + h*64 + d]
{
  constexpr int F = 1024;
  const int bid = blockIdx.x;                   // 1024 blocks
  const int wk = (bid & 7) * 128 + (bid >> 3);  // XCD-bijective swizzle
  const int i0 = (wk & 7) * 64;
  const int bh = wk >> 3;
  const int h = bh & 15;

  __shared__ __align__(16) u16 QUs[64 * 64];
  __shared__ __align__(16) u16 QVs[64 * 64];
  __shared__ __align__(16) u16 Ks[64 * 64];
  __shared__ __align__(16) u16 Vs[64 * 64];
  __shared__ __align__(16) u16 Rs[64 * 64];
  __shared__ __align__(8) u16 PBT[2][64 * 68];   // transposed band halves
  __shared__ __align__(16) u16 Ps[4][16][72];

  const int t = threadIdx.x;
  const int lane = t & 63;
  const int wq = t >> 6;
  const int l15 = lane & 15, lhi = lane >> 4;

  const u16* QUg = Qu + ((size_t)bh * 512 + i0) * 64;
  const u16* QVg = Qv + ((size_t)bh * 512 + i0) * 64;
  const u16* Kg = Kb + (size_t)bh * F * 64;
  const u16* Vg = Vt + (size_t)bh * 64 * F;
  const u16* Rg = Rh + (size_t)h * F * 64;

  auto stageT = [&](const u16* g, u16* dst) {   // 64x64 tile, row stride 64
#pragma unroll
    for (int rnd = 0; rnd < 2; ++rnd) {
      const int idx = rnd * 256 + t;
      const int row = idx >> 3;
      const int gs = (idx & 7) ^ (row & 7);
      gload16(g + row * 64 + gs * 8, dst + (size_t)(rnd * 256 + (t & 192)) * 8);
    }
  };
  auto stageVf = [&](int j0) {                  // 64 rows, stride F
#pragma unroll
    for (int rnd = 0; rnd < 2; ++rnd) {
      const int idx = rnd * 256 + t;
      const int row = idx >> 3;
      const int gs = (idx & 7) ^ (row & 7);
      gload16(Vg + (size_t)row * F + j0 + gs * 8, Vs + (size_t)(rnd * 256 + (t & 192)) * 8);
    }
  };

  // ---- prologue: QU, QV, R_lo(st=0); compute lo band -> PBT[0] ----
  stageT(QUg, QUs);
  stageT(QVg, QVs);
  const int c_lo0 = 448 - i0;
  stageT(Rg + (size_t)c_lo0 * 64, Rs);
  __syncthreads();
  {
    f32x4 pb0[4];
#pragma unroll
    for (int i = 0; i < 4; ++i) { f32x4 zz = {0.f, 0.f, 0.f, 0.f}; pb0[i] = zz; }
    __builtin_amdgcn_s_setprio(1);
#pragma unroll
    for (int ks = 0; ks < 2; ++ks) {
      const int arow = wq * 16 + l15;
      const bf16x8 av = *(const bf16x8*)&QVs[arow * 64 + (((ks * 4 + lhi) ^ (arow & 7)) << 3)];
#pragma unroll
      for (int ni = 0; ni < 4; ++ni) {
        const int brow = ni * 16 + l15;
        const bf16x8 br_ = *(const bf16x8*)&Rs[brow * 64 + (((ks * 4 + lhi) ^ (brow & 7)) << 3)];
        pb0[ni] = __builtin_amdgcn_mfma_f32_16x16x32_bf16(av, br_, pb0[ni], 0, 0, 0);
      }
    }
    __builtin_amdgcn_s_setprio(0);
#pragma unroll
    for (int ni = 0; ni < 4; ++ni) {
      u64 w = (u64)f2b(pb0[ni][0]) | ((u64)f2b(pb0[ni][1]) << 16) |
              ((u64)f2b(pb0[ni][2]) << 32) | ((u64)f2b(pb0[ni][3]) << 48);
      *(u64*)&PBT[0][(size_t)(ni * 16 + l15) * 68 + wq * 16 + lhi * 4] = w;
    }
  }

  f32x4 Oacc[4];
#pragma unroll
  for (int i = 0; i < 4; ++i) { f32x4 zz = {0.f, 0.f, 0.f, 0.f}; Oacc[i] = zz; }
  float mrow[4] = {-3.0e38f, -3.0e38f, -3.0e38f, -3.0e38f};
  float lrow[4] = {0.f, 0.f, 0.f, 0.f};

  const int nT = i0 / 64 + 9;
  for (int st = 0; st < nT; ++st) {
    const int j0 = st * 64;
    const bool lastT = (st == nT - 1);
    __syncthreads();   // A: previous compute done, safe to overwrite tiles
    stageT(Kg + (size_t)j0 * 64, Ks);
    stageVf(j0);
    if (!lastT) stageT(Rg + (size_t)(j0 - i0 + 512) * 64, Rs);
    __syncthreads();   // B: staged data visible (vmcnt drain)

    // ---- content + NEW hi-band MFMAs ----
    f32x4 cacc[4], pbh[4];
#pragma unroll
    for (int i = 0; i < 4; ++i) {
      f32x4 zz = {0.f, 0.f, 0.f, 0.f};
      cacc[i] = zz; pbh[i] = zz;
    }
    __builtin_amdgcn_s_setprio(1);
#pragma unroll
    for (int ks = 0; ks < 2; ++ks) {
      const int arow = wq * 16 + l15;
      const bf16x8 au = *(const bf16x8*)&QUs[arow * 64 + (((ks * 4 + lhi) ^ (arow & 7)) << 3)];
#pragma unroll
      for (int ni = 0; ni < 4; ++ni) {
        const int brow = ni * 16 + l15;
        const bf16x8 bk_ = *(const bf16x8*)&Ks[brow * 64 + (((ks * 4 + lhi) ^ (brow & 7)) << 3)];
        cacc[ni] = __builtin_amdgcn_mfma_f32_16x16x32_bf16(au, bk_, cacc[ni], 0, 0, 0);
      }
      if (!lastT) {
        const bf16x8 av = *(const bf16x8*)&QVs[arow * 64 + (((ks * 4 + lhi) ^ (arow & 7)) << 3)];
#pragma unroll
        for (int ni = 0; ni < 4; ++ni) {
          const int brow = ni * 16 + l15;
          const bf16x8 br_ = *(const bf16x8*)&Rs[brow * 64 + (((ks * 4 + lhi) ^ (brow & 7)) << 3)];
          pbh[ni] = __builtin_amdgcn_mfma_f32_16x16x32_bf16(av, br_, pbh[ni], 0, 0, 0);
        }
      }
    }
    __builtin_amdgcn_s_setprio(0);

    // write hi band transposed into rotating buffer (wave-local columns)
    if (!lastT) {
#pragma unroll
      for (int ni = 0; ni < 4; ++ni) {
        u64 w = (u64)f2b(pbh[ni][0]) | ((u64)f2b(pbh[ni][1]) << 16) |
                ((u64)f2b(pbh[ni][2]) << 32) | ((u64)f2b(pbh[ni][3]) << 48);
        *(u64*)&PBT[(st + 1) & 1][(size_t)(ni * 16 + l15) * 68 + wq * 16 + lhi * 4] = w;
      }
    }

    // ---- build scores: (cacc + pb) / 8 ----
    const int lim = i0 - j0 + 512;
    const u16* pbLo = &PBT[st & 1][0];
    const u16* pbHi = &PBT[(st + 1) & 1][0];
    float sc[4][4];
#pragma unroll
    for (int ni = 0; ni < 4; ++ni) {
      const int dj = ni * 16 + l15;
#pragma unroll
      for (int qq = 0; qq < 4; ++qq) {
        const int di = wq * 16 + lhi * 4 + qq;
        const int cc = dj - di + 63;                // [0,126]
        const float pb = b2f((cc < 64) ? pbLo[(size_t)cc * 68 + di]
                                       : pbHi[(size_t)(cc - 64) * 68 + di]);
        float s = (cacc[ni][qq] + pb) * 0.125f;
        if (dj - di > lim) s = -1e30f;
        sc[ni][qq] = s;
      }
    }

    // ---- online softmax (per wave; rows wave-exclusive) ----
    float nm[4], esc[4];
#pragma unroll
    for (int qq = 0; qq < 4; ++qq) {
      float r = fmaxf(fmaxf(sc[0][qq], sc[1][qq]), fmaxf(sc[2][qq], sc[3][qq]));
      r = fmaxf(r, __shfl_xor(r, 1));
      r = fmaxf(r, __shfl_xor(r, 2));
      r = fmaxf(r, __shfl_xor(r, 4));
      r = fmaxf(r, __shfl_xor(r, 8));
      nm[qq] = fmaxf(mrow[qq], r);
      esc[qq] = __expf(mrow[qq] - nm[qq]);
      mrow[qq] = nm[qq];
    }
    float ps[4][4];
    float rsum[4] = {0.f, 0.f, 0.f, 0.f};
#pragma unroll
    for (int ni = 0; ni < 4; ++ni)
#pragma unroll
      for (int qq = 0; qq < 4; ++qq) {
        float p = __expf(sc[ni][qq] - nm[qq]);
        ps[ni][qq] = p;
        rsum[qq] += p;
      }
#pragma unroll
    for (int qq = 0; qq < 4; ++qq) {
      float r = rsum[qq];
      r += __shfl_xor(r, 1);
      r += __shfl_xor(r, 2);
      r += __shfl_xor(r, 4);
      r += __shfl_xor(r, 8);
      lrow[qq] = lrow[qq] * esc[qq] + r;
    }
#pragma unroll
    for (int nd = 0; nd < 4; ++nd)
#pragma unroll
      for (int qq = 0; qq < 4; ++qq) Oacc[nd][qq] *= esc[qq];

    // ---- P -> LDS (bf16) -> PV MFMA ----
#pragma unroll
    for (int ni = 0; ni < 4; ++ni)
#pragma unroll
      for (int qq = 0; qq < 4; ++qq)
        Ps[wq][lhi * 4 + qq][ni * 16 + l15] = f2b(ps[ni][qq]);
    __builtin_amdgcn_s_setprio(1);
#pragma unroll
    for (int ks = 0; ks < 2; ++ks) {
      const bf16x8 pa = *(const bf16x8*)&Ps[wq][l15][ks * 32 + lhi * 8];
#pragma unroll
      for (int nd = 0; nd < 4; ++nd) {
        const int vrow = nd * 16 + l15;
        const bf16x8 vb_ = *(const bf16x8*)&Vs[vrow * 64 + (((ks * 4 + lhi) ^ (vrow & 7)) << 3)];
        Oacc[nd] = __builtin_amdgcn_mfma_f32_16x16x32_bf16(pa, vb_, Oacc[nd], 0, 0, 0);
      }
    }
    __builtin_amdgcn_s_setprio(0);
  }

  // epilogue: normalize and store
  float inv[4];
#pragma unroll
  for (int qq = 0; qq < 4; ++qq) inv[qq] = 1.f / lrow[qq];
  const int b = bh >> 4;
#pragma unroll
  for (int nd = 0; nd < 4; ++nd)
#pragma unroll
    for (int qq = 0; qq < 4; ++qq) {
      const int row = i0 + wq * 16 + lhi * 4 + qq;
      const int d = nd * 16 + l15;
      Y[(size_t)row * 8192 + b * 1024 + h * 64 + d] = f2b(Oacc[nd][qq] * inv[qq]);
    }
}

// ---------------------------------------------------------------------------
// bias prep: bqu = bq + u_flat ; dvb = vb_flat - u_flat   (1024 each)
// ---------------------------------------------------------------------------
__global__ __launch_bounds__(256) void biasprep(const float* __restrict__ bq,
                                                const float* __restrict__ u,
                                                const float* __restrict__ vb,
                                                float* __restrict__ bqu,
                                                float* __restrict__ dvb)
{
  const int i = blockIdx.x * 256 + threadIdx.x;
  bqu[i] = bq[i] + u[i];
  dvb[i] = vb[i] - u[i];
}

// QV[idx] = QU[idx] + dvb[h*64+d]   over [b][h][s][64]
__global__ __launch_bounds__(256) void qv_make(const u16* __restrict__ QU,
                                               const float* __restrict__ dvb,
                                               u16* __restrict__ QV)
{
  const long long idx = (long long)blockIdx.x * 256 + threadIdx.x;
  const int d = idx & 63;
  const int h = (idx >> 15) & 15;
  QV[idx] = f2b(b2f(QU[idx]) + dvb[h * 64 + d]);
}

// ---------------------------------------------------------------------------
// Weight transpose+convert: src (K x N) f32  ->  dst (N x K) bf16. Dims %32==0.
// ---------------------------------------------------------------------------
#define MAXW 20
struct WPack {
  const float* src[MAXW];
  u16* dst[MAXW];
  int K[MAXW], N[MAXW];
  int tilePrefix[MAXW + 1];
  int nm;
};

__global__ __launch_bounds__(256) void wtrans_kernel(WPack p) {
  int bid = blockIdx.x;
  int m = 0;
  while (m < p.nm && bid >= p.tilePrefix[m + 1]) ++m;
  if (m >= p.nm) return;
  const int lt = bid - p.tilePrefix[m];
  const int K = p.K[m], N = p.N[m];
  const int tN = N >> 5;
  const int kt = lt / tN, nt = lt - kt * tN;
  const int k0 = kt << 5, n0 = nt << 5;
  const float* src = p.src[m];
  u16* dst = p.dst[m];
  __shared__ float tile[32][33];
  const int t = threadIdx.x;
  const int r = t >> 3, c4 = (t & 7) << 2;
  float4 v = *(const float4*)&src[(size_t)(k0 + r) * N + n0 + c4];
  tile[r][c4 + 0] = v.x; tile[r][c4 + 1] = v.y; tile[r][c4 + 2] = v.z; tile[r][c4 + 3] = v.w;
  __syncthreads();
  u16 o0 = f2b(tile[c4 + 0][r]);
  u16 o1 = f2b(tile[c4 + 1][r]);
  u16 o2 = f2b(tile[c4 + 2][r]);
  u16 o3 = f2b(tile[c4 + 3][r]);
  u64 w = (u64)o0 | ((u64)o1 << 16) | ((u64)o2 << 32) | ((u64)o3 << 48);
  *(u64*)&dst[(size_t)(n0 + r) * K + k0 + c4] = w;
}

// ---------------------------------------------------------------------------
// LayerNorm over D=1024; rows [0,rowsMem) from Xmem, rest from Xout. bf16 out.
// ---------------------------------------------------------------------------
__global__ __launch_bounds__(256) void ln_kernel(
    const float* __restrict__ Xmem, const float* __restrict__ Xout, int rowsMem,
    const float* __restrict__ sc, const float* __restrict__ bi, u16* __restrict__ dst)
{
  const int row = blockIdx.x;
  const float* src = (row < rowsMem) ? (Xmem + (long long)row * 1024)
                                     : (Xout + (long long)(row - rowsMem) * 1024);
  const int t = threadIdx.x;
  float4 v = *(const float4*)&src[t * 4];
  float s1 = v.x + v.y + v.z + v.w;
  float s2 = v.x * v.x + v.y * v.y + v.z * v.z + v.w * v.w;
#pragma unroll
  for (int o = 32; o > 0; o >>= 1) { s1 += __shfl_down(s1, o); s2 += __shfl_down(s2, o); }
  __shared__ float red[8];
  const int wv = t >> 6;
  if ((t & 63) == 0) { red[wv * 2] = s1; red[wv * 2 + 1] = s2; }
  __syncthreads();
  s1 = red[0] + red[2] + red[4] + red[6];
  s2 = red[1] + red[3] + red[5] + red[7];
  const float mu = s1 * (1.f / 1024.f);
  const float var = s2 * (1.f / 1024.f) - mu * mu;
  const float rs = rsqrtf(var + 1e-5f);
  float vals[4] = {v.x, v.y, v.z, v.w};
  u16 o4[4];
#pragma unroll
  for (int j = 0; j < 4; ++j) {
    const int c = t * 4 + j;
    o4[j] = f2b((vals[j] - mu) * rs * sc[c] + bi[c]);
  }
  *(u64*)&dst[(long long)row * 1024 + t * 4] =
      (u64)o4[0] | ((u64)o4[1] << 16) | ((u64)o4[2] << 32) | ((u64)o4[3] << 48);
}

// ---------------------------------------------------------------------------
// small prep / elementwise kernels
// ---------------------------------------------------------------------------
__global__ __launch_bounds__(256) void prep_vt16(const u16* __restrict__ Vf, u16* __restrict__ VT)
{
  const int f0 = blockIdx.x * 64;
  const int bh = blockIdx.y;
  const int b = bh >> 4, h = bh & 15;
  __shared__ u16 tl[64 * 64];
  const int t = threadIdx.x;
  {
    const int fr = t >> 2, c0 = (t & 3) * 16;
    const u16* src = Vf + ((size_t)(f0 + fr) * 8 + b) * 1024 + h * 64 + c0;
    *(bf16x8*)&tl[fr * 64 + c0] = *(const bf16x8*)src;
    *(bf16x8*)&tl[fr * 64 + c0 + 8] = *(const bf16x8*)(src + 8);
  }
  __syncthreads();
  {
    const int dr = t >> 2, c0 = (t & 3) * 16;
    u16* dst = VT + ((long long)bh * 64 + dr) * 1024 + f0 + c0;
#pragma unroll
    for (int j = 0; j < 16; ++j) dst[j] = tl[(c0 + j) * 64 + dr];
  }
}

__global__ __launch_bounds__(256) void pe_kernel(u16* __restrict__ PEB)
{
  const long long idx = (long long)blockIdx.x * 256 + threadIdx.x;  // F*D
  const int p = (int)(idx >> 10);
  const int d = idx & 1023;
  const int q = d & 511;
  const float inv = powf(10000.f, -(float)(2 * q) * (1.f / 1024.f));
  const float ang = (float)(1023 - p) * inv;
  PEB[idx] = f2b((d < 512) ? sinf(ang) : cosf(ang));
}

__global__ __launch_bounds__(256) void embed_conv(const float* __restrict__ h, u16* __restrict__ A)
{
  const long long idx = (long long)blockIdx.x * 256 + threadIdx.x;  // SB*IN
  const int c = idx & 127;
  const int r = (int)(idx >> 7);
  const int s = r >> 3, b = r & 7;
  A[idx] = f2b(h[(((long long)b * 512 + s) << 7) + c]);
}

__global__ __launch_bounds__(256) void gru_elemA(const float* __restrict__ T1, float* __restrict__ T2,
                                                 const float* __restrict__ X, u16* __restrict__ RXBF)
{
  const long long i4 = ((long long)blockIdx.x * 256 + threadIdx.x) * 4;  // SB*D
  const int row = (int)(i4 >> 10);
  const int c = i4 & 1023;
  const float* t1 = T1 + (long long)row * 3072 + c;
  float* t2 = T2 + (long long)row * 2048 + c;
  float4 ry = *(const float4*)t1;
  float4 zy = *(const float4*)(t1 + 1024);
  float4 rx = *(const float4*)t2;
  float4 zx = *(const float4*)(t2 + 1024);
  float4 x = *(const float4*)(X + i4);
  float rr[4], zz[4];
  rr[0] = sigm_f(ry.x + rx.x); rr[1] = sigm_f(ry.y + rx.y);
  rr[2] = sigm_f(ry.z + rx.z); rr[3] = sigm_f(ry.w + rx.w);
  zz[0] = sigm_f(zy.x + zx.x - 2.f); zz[1] = sigm_f(zy.y + zx.y - 2.f);
  zz[2] = sigm_f(zy.z + zx.z - 2.f); zz[3] = sigm_f(zy.w + zx.w - 2.f);
  u16 o4[4];
  o4[0] = f2b(rr[0] * x.x); o4[1] = f2b(rr[1] * x.y);
  o4[2] = f2b(rr[2] * x.z); o4[3] = f2b(rr[3] * x.w);
  *(u64*)&RXBF[i4] = (u64)o4[0] | ((u64)o4[1] << 16) | ((u64)o4[2] << 32) | ((u64)o4[3] << 48);
  float4 zo; zo.x = zz[0]; zo.y = zz[1]; zo.z = zz[2]; zo.w = zz[3];
  *(float4*)t2 = zo;
}

__global__ __launch_bounds__(256) void gru_elemB(const float* __restrict__ T1, const float* __restrict__ T2,
                                                 const float* __restrict__ TG, const float* __restrict__ X,
                                                 float* __restrict__ O, u16* __restrict__ XBF)
{
  const long long i4 = ((long long)blockIdx.x * 256 + threadIdx.x) * 4;
  const int row = (int)(i4 >> 10);
  const int c = i4 & 1023;
  float4 gy = *(const float4*)(T1 + (long long)row * 3072 + 2048 + c);
  float4 tt = *(const float4*)(TG + i4);
  float4 z = *(const float4*)(T2 + (long long)row * 2048 + c);
  float4 x = *(const float4*)(X + i4);
  float4 o;
  o.x = (1.f - z.x) * x.x + z.x * tanh_f(gy.x + tt.x);
  o.y = (1.f - z.y) * x.y + z.y * tanh_f(gy.y + tt.y);
  o.z = (1.f - z.z) * x.z + z.z * tanh_f(gy.z + tt.z);
  o.w = (1.f - z.w) * x.w + z.w * tanh_f(gy.w + tt.w);
  *(float4*)(O + i4) = o;
  u16 o4[4];
  o4[0] = f2b(o.x); o4[1] = f2b(o.y); o4[2] = f2b(o.z); o4[3] = f2b(o.w);
  *(u64*)&XBF[i4] = (u64)o4[0] | ((u64)o4[1] << 16) | ((u64)o4[2] << 32) | ((u64)o4[3] << 48);
}

__global__ __launch_bounds__(256) void out_transpose(const float* __restrict__ O, float* __restrict__ dst)
{
  const long long i4 = ((long long)blockIdx.x * 256 + threadIdx.x) * 4;
  const int d = i4 & 1023;
  const int r = (int)(i4 >> 10);
  const int s = r >> 3, b = r & 7;
  float4 v = *(const float4*)(O + i4);
  *(float4*)&dst[(((long long)b * 512 + s) << 10) + d] = v;
}

// ---------------------------------------------------------------------------
extern "C" void kernel_launch(void* const* d_in, const int* in_sizes, int n_in,
                              void* d_out, int out_size, void* d_ws, size_t ws_size,
                              hipStream_t stream)
{
  (void)in_sizes; (void)n_in; (void)out_size; (void)ws_size;
  const float* h_in   = (const float*)d_in[0];
  const float* memory = (const float*)d_in[1];
  const float* We     = (const float*)d_in[2];
  const float* be     = (const float*)d_in[3];
  const float* ln1s   = (const float*)d_in[4];
  const float* ln1b   = (const float*)d_in[5];
  const float* ln2s   = (const float*)d_in[6];
  const float* ln2b   = (const float*)d_in[7];
  const float* Wq     = (const float*)d_in[8];
  const float* bq     = (const float*)d_in[9];
  const float* Wk     = (const float*)d_in[10];
  const float* bk     = (const float*)d_in[11];
  const float* Wv     = (const float*)d_in[12];
  const float* bv     = (const float*)d_in[13];
  const float* Wr     = (const float*)d_in[14];
  const float* br     = (const float*)d_in[15];
  const float* Wo     = (const float*)d_in[16];
  const float* bo     = (const float*)d_in[17];
  const float* uu     = (const float*)d_in[18];
  const float* vbp    = (const float*)d_in[19];
  const float* gWr    = (const float*)d_in[20];
  const float* gUr    = (const float*)d_in[21];
  const float* gWz    = (const float*)d_in[22];
  const float* gUz    = (const float*)d_in[23];
  const float* gWg    = (const float*)d_in[24];
  const float* gUg    = (const float*)d_in[25];
  const float* fW1    = (const float*)d_in[26];
  const float* fb1    = (const float*)d_in[27];
  const float* fW2    = (const float*)d_in[28];
  const float* fb2    = (const float*)d_in[29];

  constexpr int S = 512, MM = 512, B = 8, D = 1024, H = 16, IN = 128, F = 1024;
  constexpr int SB = 4096, FB = 8192;
  constexpr long long DD = (long long)D * D;

  char* ws = (char*)d_ws;
  size_t off = 0;
  auto alloc = [&](size_t bytes) -> size_t {
    size_t o = off; off = (off + bytes + 255) & ~(size_t)255; return o;
  };
  const size_t oWT   = alloc((size_t)25 * DD * 2);
  const size_t oWET  = alloc((size_t)D * IN * 2);
  const size_t oPEB  = alloc((size_t)F * D * 2);
  const size_t oOUT  = alloc((size_t)SB * D * 4);
  const size_t oOUT1 = alloc((size_t)SB * D * 4);
  const size_t oXBF  = alloc((size_t)SB * D * 2);
  const size_t oYBF  = alloc((size_t)SB * D * 2);
  const size_t oYBFA = alloc((size_t)SB * D * 2);
  const size_t oABUF = alloc((size_t)SB * D * 2);
  const size_t oKN   = alloc((size_t)FB * D * 2);
  const size_t oQU   = alloc((size_t)B * H * S * 64 * 2);
  const size_t oQV   = alloc((size_t)B * H * S * 64 * 2);
  const size_t oKBH  = alloc((size_t)B * H * F * 64 * 2);
  const size_t oVT   = alloc((size_t)B * H * F * 64 * 2);
  const size_t oRH   = alloc((size_t)H * F * 64 * 2);
  const size_t oBQU  = alloc((size_t)D * 4);
  const size_t oDVB  = alloc((size_t)D * 4);
  const size_t oUNI  = off;

  u16* WTp   = (u16*)(ws + oWT);
  u16* WETp  = (u16*)(ws + oWET);
  u16* PEBp  = (u16*)(ws + oPEB);
  float* OUTp  = (float*)(ws + oOUT);
  float* OUT1p = (float*)(ws + oOUT1);
  u16* XBFp  = (u16*)(ws + oXBF);
  u16* YBFp  = (u16*)(ws + oYBF);
  u16* YBFAp = (u16*)(ws + oYBFA);
  u16* ABUFp = (u16*)(ws + oABUF);
  u16* KNp   = (u16*)(ws + oKN);
  u16* QUp   = (u16*)(ws + oQU);
  u16* QVp   = (u16*)(ws + oQV);
  u16* KBHp  = (u16*)(ws + oKBH);
  u16* VTp   = (u16*)(ws + oVT);
  u16* RHp   = (u16*)(ws + oRH);
  float* bquP = (float*)(ws + oBQU);
  float* dvbP = (float*)(ws + oDVB);
  u16* VF16p  = (u16*)(ws + oUNI);
  float* T1   = (float*)(ws + oUNI);
  float* T2   = (float*)(ws + oUNI + (size_t)SB * 3 * D * 4);
  float* TGp  = (float*)(ws + oUNI + (size_t)SB * 5 * D * 4);
  u16* FFNBp  = (u16*)(ws + oUNI);

  auto gemm = [&](const u16* A, const u16* Bt, const float* bias, float* C32, u16* C16,
                  int M, int N, int K, int ldA, int ldB, int ldC,
                  long long sA, long long sBb, long long sBh, long long sC, int nH, int Z,
                  int flags) {
    if (N <= 1024) {
      dim3 grid((M + 127) / 128, (N + 63) / 64, Z);
      gemm_bt<64><<<grid, 256, 0, stream>>>(A, Bt, bias, C32, C16, M, N, K, ldA, ldB, ldC,
                                            sA, sBb, sBh, sC, nH, flags);
    } else {
      dim3 grid((M + 127) / 128, (N + 127) / 128, Z);
      gemm_bt<128><<<grid, 256, 0, stream>>>(A, Bt, bias, C32, C16, M, N, K, ldA, ldB, ldC,
                                             sA, sBb, sBh, sC, nH, flags);
    }
  };

  pe_kernel<<<(F * D) / 256, 256, 0, stream>>>(PEBp);
  {
    WPack p{};
    p.nm = 1; p.src[0] = We; p.dst[0] = WETp; p.K[0] = IN; p.N[0] = D;
    p.tilePrefix[0] = 0; p.tilePrefix[1] = (IN / 32) * (D / 32);
    wtrans_kernel<<<p.tilePrefix[1], 256, 0, stream>>>(p);
  }
  embed_conv<<<(SB * IN) / 256, 256, 0, stream>>>(h_in, ABUFp);
  gemm(ABUFp, WETp, be, OUTp, XBFp, SB, D, IN, IN, IN, D, 0, 0, 0, 0, 1, 1, 1 | 2 | 4 | 8);

  for (int li = 0; li < 4; ++li) {
    WPack p{};
    int nt = 0, id = 0;
    auto addw = [&](const float* s, u16* d, int K, int N) {
      p.src[id] = s; p.dst[id] = d; p.K[id] = K; p.N[id] = N;
      p.tilePrefix[id] = nt; nt += (K / 32) * (N / 32); ++id;
    };
    addw(Wq + li * DD, WTp + 0 * DD, D, D);
    addw(Wk + li * DD, WTp + 1 * DD, D, D);
    addw(Wv + li * DD, WTp + 2 * DD, D, D);
    addw(Wr + li * DD, WTp + 3 * DD, D, D);
    addw(Wo + li * DD, WTp + 4 * DD, D, D);
    addw(gWr + (li * 2 + 0) * DD, WTp + 5 * DD, D, D);
    addw(gWz + (li * 2 + 0) * DD, WTp + 6 * DD, D, D);
    addw(gWg + (li * 2 + 0) * DD, WTp + 7 * DD, D, D);
    addw(gUr + (li * 2 + 0) * DD, WTp + 8 * DD, D, D);
    addw(gUz + (li * 2 + 0) * DD, WTp + 9 * DD, D, D);
    addw(gUg + (li * 2 + 0) * DD, WTp + 10 * DD, D, D);
    addw(gWr + (li * 2 + 1) * DD, WTp + 11 * DD, D, D);
    addw(gWz + (li * 2 + 1) * DD, WTp + 12 * DD, D, D);
    addw(gWg + (li * 2 + 1) * DD, WTp + 13 * DD, D, D);
    addw(gUr + (li * 2 + 1) * DD, WTp + 14 * DD, D, D);
    addw(gUz + (li * 2 + 1) * DD, WTp + 15 * DD, D, D);
    addw(gUg + (li * 2 + 1) * DD, WTp + 16 * DD, D, D);
    addw(fW1 + li * (long long)D * 4096, WTp + 17 * DD, D, 4096);
    addw(fW2 + li * (long long)4096 * D, WTp + 21 * DD, 4096, D);
    p.tilePrefix[id] = nt; p.nm = id;
    wtrans_kernel<<<nt, 256, 0, stream>>>(p);

    ln_kernel<<<FB, 256, 0, stream>>>(memory + (long long)li * MM * B * D, OUTp, MM * B,
                                      ln1s + li * D, ln1b + li * D, KNp);
    const u16* QN = KNp + (size_t)MM * B * D;

    // ---- projections: head-layout bf16 epilogues; u/vb folded into Q ----
    biasprep<<<4, 256, 0, stream>>>(bq + li * D, uu + li * D, vbp + li * D, bquP, dvbP);
    gemm(QN, WTp + 0 * DD, bquP, nullptr, QUp, SB, D, D, D, D, /*seq*/ S,
         0, 0, 0, 0, 1, 1, 2 | 8 | 16);
    qv_make<<<(B * H * S * 64) / 256, 256, 0, stream>>>(QUp, dvbP, QVp);
    gemm(KNp, WTp + 1 * DD, bk + li * D, nullptr, KBHp, FB, D, D, D, D, /*seq*/ F,
         0, 0, 0, 0, 1, 1, 2 | 8 | 16);
    gemm(KNp, WTp + 2 * DD, bv + li * D, nullptr, VF16p, FB, D, D, D, D, D,
         0, 0, 0, 0, 1, 1, 2 | 8);
    prep_vt16<<<dim3(F / 64, B * H), 256, 0, stream>>>(VF16p, VTp);
    gemm(PEBp, WTp + 3 * DD, br + li * D, nullptr, RHp, F, D, D, D, D, D,
         0, 0, 0, 0, 1, 1, 2 | 8 | 32);

    // ---- fused attention ----
    fused_attn<<<dim3((S / 64) * B * H), 256, 0, stream>>>(QUp, QVp, KBHp, VTp, RHp, YBFAp);

    // ---- output projection: y = gelu(attn @ Wo + bo) ----
    gemm(YBFAp, WTp + 4 * DD, bo + li * D, nullptr, YBFp, SB, D, D, D, D, D, 0, 0, 0, 0, 1, 1, 1 | 2 | 8);

    // ---- GRU1 ----
    gemm(YBFp, WTp + 5 * DD, nullptr, T1, nullptr, SB, 3 * D, D, D, D, 3 * D, 0, 0, 0, 0, 1, 1, 4);
    gemm(XBFp, WTp + 8 * DD, nullptr, T2, nullptr, SB, 2 * D, D, D, D, 2 * D, 0, 0, 0, 0, 1, 1, 4);
    gru_elemA<<<(SB * D / 4) / 256, 256, 0, stream>>>(T1, T2, OUTp, ABUFp);
    gemm(ABUFp, WTp + 10 * DD, nullptr, TGp, nullptr, SB, D, D, D, D, D, 0, 0, 0, 0, 1, 1, 4);
    gru_elemB<<<(SB * D / 4) / 256, 256, 0, stream>>>(T1, T2, TGp, OUTp, OUT1p, XBFp);

    // ---- FFN ----
    ln_kernel<<<SB, 256, 0, stream>>>(OUT1p, OUT1p, SB, ln2s + li * D, ln2b + li * D, ABUFp);
    gemm(ABUFp, WTp + 17 * DD, fb1 + li * 4096, nullptr, FFNBp, SB, 4096, D, D, D, 4096,
         0, 0, 0, 0, 1, 1, 1 | 2 | 8);
    gemm(FFNBp, WTp + 21 * DD, fb2 + li * D, nullptr, YBFp, SB, D, 4096, 4096, 4096, D,
         0, 0, 0, 0, 1, 1, 1 | 2 | 8);

    // ---- GRU2 ----
    gemm(YBFp, WTp + 11 * DD, nullptr, T1, nullptr, SB, 3 * D, D, D, D, 3 * D, 0, 0, 0, 0, 1, 1, 4);
    gemm(XBFp, WTp + 14 * DD, nullptr, T2, nullptr, SB, 2 * D, D, D, D, 2 * D, 0, 0, 0, 0, 1, 1, 4);
    gru_elemA<<<(SB * D / 4) / 256, 256, 0, stream>>>(T1, T2, OUT1p, ABUFp);
    gemm(ABUFp, WTp + 16 * DD, nullptr, TGp, nullptr, SB, D, D, D, D, D, 0, 0, 0, 0, 1, 1, 4);
    gru_elemB<<<(SB * D / 4) / 256, 256, 0, stream>>>(T1, T2, TGp, OUT1p, OUTp, XBFp);
  }

  out_transpose<<<(SB * D / 4) / 256, 256, 0, stream>>>(OUTp, (float*)d_out);
}